// Round 2
// baseline (41410.794 us; speedup 1.0000x reference)
//
#include <hip/hip_runtime.h>

// ---------------------------------------------------------------------------
// DA-RNN forward, adaptive workspace plan.
//   prep_k    : transpose all weights for coalesced column access + bias sums
//   ux_k      : Ux[b][i][s]  = sum_t x[b,t,i] *Ue[s,t]      (encoder attn, hoisted)
//   encoder_k : 128 sequential steps, 4 batch rows / wg, states in LDS
//   udx_k     : Udx[b][t][k] = sum_m x1[b,t,m]*Ud[k,m]      (decoder attn, hoisted)
//   decoder_k : 128 sequential steps + final head
// Batch-independent recurrence => no inter-workgroup sync anywhere.
// Workspace: [weights (1,067,008 f)] [X1: CB*32768 f] [shared UX/UDX: CB*32768 f]
// UX is dead after encoder_k, so UDX reuses its region (stream-ordered).
// Batch processed in 1024/CB chunks; CB chosen largest fitting ws_size.
// ---------------------------------------------------------------------------

#define O_WET     0u
#define O_WENC    65536u       // [384][1024] = [Wih_e^T ; Whh_e^T]
#define O_WDT     458752u      // [512][256]
#define O_WHHTD   589824u      // [256][1024]
#define O_W1T     851968u      // [512][256]
#define O_UDT     983040u      // [256][256]  UdT[m][k] = Ud[k][m]
#define O_UET     1048576u     // [128][128]  UeT[t][s] = Ue[s][t]
#define O_BENC    1064960u
#define O_BDEC    1065984u
#define W_FLOATS  1067008u

#define FMA4(acc, s, w) \
  acc.x = fmaf((s), (w).x, acc.x); \
  acc.y = fmaf((s), (w).y, acc.y); \
  acc.z = fmaf((s), (w).z, acc.z); \
  acc.w = fmaf((s), (w).w, acc.w);

__device__ __forceinline__ float fsig(float x) {
  return __builtin_amdgcn_rcpf(1.f + __expf(-x));
}
__device__ __forceinline__ float fth(float x) {
  float e2 = __expf(2.f * x);
  return 1.f - 2.f * __builtin_amdgcn_rcpf(e2 + 1.f);
}

// reduce over the 128 threads of a row-group (2 waves). red[] >= 8 floats.
__device__ __forceinline__ float rowreduce_sum(float v, float* red) {
  #pragma unroll
  for (int o = 32; o > 0; o >>= 1) v += __shfl_xor(v, o);
  __syncthreads();                       // protect red[] from previous use
  int w = threadIdx.x >> 6;
  if ((threadIdx.x & 63) == 0) red[w] = v;
  __syncthreads();
  int wb = w & ~1;
  return red[wb] + red[wb + 1];
}
__device__ __forceinline__ float rowreduce_max(float v, float* red) {
  #pragma unroll
  for (int o = 32; o > 0; o >>= 1) v = fmaxf(v, __shfl_xor(v, o));
  __syncthreads();
  int w = threadIdx.x >> 6;
  if ((threadIdx.x & 63) == 0) red[w] = v;
  __syncthreads();
  int wb = w & ~1;
  return fmaxf(red[wb], red[wb + 1]);
}

// ---------------------------------------------------------------------------
__global__ __launch_bounds__(256) void prep_k(
    const float* __restrict__ We,    const float* __restrict__ Wih_e,
    const float* __restrict__ Whh_e, const float* __restrict__ Wd,
    const float* __restrict__ Whh_d, const float* __restrict__ W1,
    const float* __restrict__ Ud,    const float* __restrict__ Ue,
    const float* __restrict__ bih_e, const float* __restrict__ bhh_e,
    const float* __restrict__ bih_d, const float* __restrict__ bhh_d,
    float* __restrict__ ws)
{
  unsigned idx = blockIdx.x * 256u + threadIdx.x;
  if (idx >= W_FLOATS) return;
  if (idx < 65536u) {                       // WeT[k*128+j] = We[j*512+k]
    unsigned k = idx >> 7, j = idx & 127u;
    ws[O_WET + idx] = We[j * 512u + k];
  } else if (idx < 196608u) {               // Wenc rows 0..127 = Wih_e^T
    unsigned rel = idx - 65536u;
    unsigned k = rel >> 10, j = rel & 1023u;
    ws[O_WENC + rel] = Wih_e[j * 128u + k];
  } else if (idx < 458752u) {               // Wenc rows 128..383 = Whh_e^T
    unsigned rel = idx - 196608u;
    unsigned k = rel >> 10, j = rel & 1023u;
    ws[O_WENC + 131072u + rel] = Whh_e[j * 256u + k];
  } else if (idx < 589824u) {               // WdT[k*256+j] = Wd[j*512+k]
    unsigned rel = idx - 458752u;
    unsigned k = rel >> 8, j = rel & 255u;
    ws[O_WDT + rel] = Wd[j * 512u + k];
  } else if (idx < 851968u) {               // WhhTd[k*1024+j] = Whh_d[j*256+k]
    unsigned rel = idx - 589824u;
    unsigned k = rel >> 10, j = rel & 1023u;
    ws[O_WHHTD + rel] = Whh_d[j * 256u + k];
  } else if (idx < 983040u) {               // W1T[k*256+q] = W1[q*512+k]
    unsigned rel = idx - 851968u;
    unsigned k = rel >> 8, q = rel & 255u;
    ws[O_W1T + rel] = W1[q * 512u + k];
  } else if (idx < 1048576u) {              // UdT[m*256+k] = Ud[k*256+m]
    unsigned rel = idx - 983040u;
    unsigned m = rel >> 8, k = rel & 255u;
    ws[O_UDT + rel] = Ud[k * 256u + m];
  } else if (idx < 1064960u) {              // UeT[t*128+s] = Ue[s*128+t]
    unsigned rel = idx - 1048576u;
    unsigned t = rel >> 7, s = rel & 127u;
    ws[O_UET + rel] = Ue[s * 128u + t];
  } else if (idx < 1065984u) {
    unsigned rel = idx - 1064960u;
    ws[O_BENC + rel] = bih_e[rel] + bhh_e[rel];
  } else {
    unsigned rel = idx - 1065984u;
    ws[O_BDEC + rel] = bih_d[rel] + bhh_d[rel];
  }
}

// ---------------------------------------------------------------------------
// Ux[b][i][s] = sum_t x[b][t][i] * Ue[s][t].  grid = CB b * 4 i-chunks.
// Pointers are chunk-local.
__global__ __launch_bounds__(256) void ux_k(
    const float* __restrict__ x, const float* __restrict__ UeT,
    float* __restrict__ Ux)
{
  __shared__ float xs[128][32];
  const int b  = blockIdx.x >> 2;
  const int i0 = (blockIdx.x & 3) * 32;
  const int tid = threadIdx.x;
  for (int idx = tid; idx < 4096; idx += 256) {
    int t = idx >> 5, il = idx & 31;
    xs[t][il] = x[(size_t)b * 16384 + t * 128 + i0 + il];
  }
  __syncthreads();
  const int sl = tid & 31;   // float4 index over s (128 = 32 f4)
  const int ig = tid >> 5;   // 0..7
  const float4* UeT4 = (const float4*)UeT;
  float4 acc[4];
  #pragma unroll
  for (int ii = 0; ii < 4; ++ii) acc[ii] = make_float4(0.f, 0.f, 0.f, 0.f);
  for (int t = 0; t < 128; ++t) {
    float4 w = UeT4[t * 32 + sl];
    #pragma unroll
    for (int ii = 0; ii < 4; ++ii) {
      float a = xs[t][ig + 8 * ii];
      FMA4(acc[ii], a, w);
    }
  }
  float4* Ux4 = (float4*)Ux;
  #pragma unroll
  for (int ii = 0; ii < 4; ++ii) {
    int i_loc = ig + 8 * ii;
    Ux4[((size_t)b * 128 + i0 + i_loc) * 32 + sl] = acc[ii];
  }
}

// ---------------------------------------------------------------------------
// Udx[b][t][k] = sum_m x1[b][t][m] * Ud[k][m].  grid = CB b * 4 t-chunks.
__global__ __launch_bounds__(256) void udx_k(
    const float* __restrict__ x1, const float* __restrict__ UdT,
    float* __restrict__ Udx)
{
  __shared__ float xs[32][256];
  const int b  = blockIdx.x >> 2;
  const int t0 = (blockIdx.x & 3) * 32;
  const int tid = threadIdx.x;
  for (int idx = tid; idx < 8192; idx += 256) {
    int tl = idx >> 8, m = idx & 255;
    xs[tl][m] = x1[(size_t)b * 32768 + (t0 + tl) * 256 + m];
  }
  __syncthreads();
  const int kl = tid & 63;   // f4 over k (256 = 64 f4)
  const int tg = tid >> 6;   // 0..3
  const float4* UdT4 = (const float4*)UdT;
  float4 acc[8];
  #pragma unroll
  for (int tt = 0; tt < 8; ++tt) acc[tt] = make_float4(0.f, 0.f, 0.f, 0.f);
  for (int m = 0; m < 256; ++m) {
    float4 w = UdT4[m * 64 + kl];
    #pragma unroll
    for (int tt = 0; tt < 8; ++tt) {
      float a = xs[tg + 4 * tt][m];
      FMA4(acc[tt], a, w);
    }
  }
  float4* Udx4 = (float4*)Udx;
  #pragma unroll
  for (int tt = 0; tt < 8; ++tt) {
    Udx4[((size_t)b * 128 + t0 + tg + 4 * tt) * 64 + kl] = acc[tt];
  }
}

// ---------------------------------------------------------------------------
// Encoder: CB/4 blocks * 512 threads, 4 batch rows per block, 128 steps.
__global__ __launch_bounds__(512) void encoder_k(
    const float* __restrict__ WeT, const float* __restrict__ Wenc,
    const float* __restrict__ benc, const float* __restrict__ Ve,
    const float* __restrict__ Ux, float* __restrict__ x1)
{
  __shared__ __align__(16) float hsT[512][4];   // [h(256); cell(256)] x 4 rows
  __shared__ __align__(16) float part[8192];
  __shared__ float ohs[4][128];
  __shared__ __align__(16) float xtT[128][4];
  __shared__ float bencS[1024];
  __shared__ float red[8];

  const int tid = threadIdx.x;
  const int b0 = blockIdx.x * 4;

  for (int i = tid; i < 2048; i += 512) ((float*)hsT)[i] = 0.f;
  for (int i = tid; i < 1024; i += 512) bencS[i] = benc[i];
  __syncthreads();

  const float4* WeT4  = (const float4*)WeT;
  const float4* Wenc4 = (const float4*)Wenc;
  const float4* hsT4  = (const float4*)hsT;
  const float4* xtT4  = (const float4*)xtT;
  float4* part4 = (float4*)part;

  const int rB = tid >> 7, iB = tid & 127;
  const float4* uxB = (const float4*)Ux + ((size_t)(b0 + rB) * 128 + iB) * 32;
  float* x1B = x1 + (size_t)b0 * 32768;

  for (int step = 0; step < 128; ++step) {
    // --- Phase A: ohs[r][j] = sum_k hs[r][k]*We[j][k], K=512 split 16 ways
    {
      const int l = tid & 31, ks = tid >> 5;
      float4 a0 = {0,0,0,0}, a1 = {0,0,0,0}, a2 = {0,0,0,0}, a3 = {0,0,0,0};
      const int kb = ks * 32;
      #pragma unroll 4
      for (int k = kb; k < kb + 32; ++k) {
        float4 w  = WeT4[k * 32 + l];
        float4 hv = hsT4[k];
        FMA4(a0, hv.x, w); FMA4(a1, hv.y, w); FMA4(a2, hv.z, w); FMA4(a3, hv.w, w);
      }
      part4[(ks * 4 + 0) * 32 + l] = a0;
      part4[(ks * 4 + 1) * 32 + l] = a1;
      part4[(ks * 4 + 2) * 32 + l] = a2;
      part4[(ks * 4 + 3) * 32 + l] = a3;
    }
    __syncthreads();
    {
      const int r = tid >> 7, j = tid & 127;
      float acc = 0.f;
      #pragma unroll
      for (int ks = 0; ks < 16; ++ks) acc += part[(ks * 4 + r) * 128 + j];
      ohs[r][j] = acc;
    }
    __syncthreads();
    // --- Phase B: e[r][i] = sum_s Ve[s]*tanh(ohs[r][s] + Ux[b][i][s])
    float e_val;
    {
      float acc = 0.f;
      #pragma unroll 4
      for (int s4 = 0; s4 < 32; ++s4) {
        float4 u = uxB[s4];
        const int s = s4 * 4;
        acc = fmaf(Ve[s + 0], fth(ohs[rB][s + 0] + u.x), acc);
        acc = fmaf(Ve[s + 1], fth(ohs[rB][s + 1] + u.y), acc);
        acc = fmaf(Ve[s + 2], fth(ohs[rB][s + 2] + u.z), acc);
        acc = fmaf(Ve[s + 3], fth(ohs[rB][s + 3] + u.w), acc);
      }
      e_val = acc;
    }
    // --- softmax over i, faithful quirk: xt = alpha * e
    float mx = rowreduce_max(e_val, red);
    float p  = __expf(e_val - mx);
    float sm = rowreduce_sum(p, red);
    xtT[iB][rB] = p * __builtin_amdgcn_rcpf(sm) * e_val;
    __syncthreads();
    // --- Phase D: gates z = [xt;h] @ Wenc, K=384 split 2 ways
    {
      const int jl = tid & 255, ks = tid >> 8;
      float4 a0 = {0,0,0,0}, a1 = {0,0,0,0}, a2 = {0,0,0,0}, a3 = {0,0,0,0};
      const int kb = ks * 192, ke = kb + 192;
      for (int k = kb; k < ke; ++k) {
        float4 w  = Wenc4[k * 256 + jl];
        float4 av = (k < 128) ? xtT4[k] : hsT4[k - 128];
        FMA4(a0, av.x, w); FMA4(a1, av.y, w); FMA4(a2, av.z, w); FMA4(a3, av.w, w);
      }
      part4[(ks * 4 + 0) * 256 + jl] = a0;
      part4[(ks * 4 + 1) * 256 + jl] = a1;
      part4[(ks * 4 + 2) * 256 + jl] = a2;
      part4[(ks * 4 + 3) * 256 + jl] = a3;
    }
    __syncthreads();
    // --- update: i,f,g,o -> h2, c2; write h2 to x1
    {
      #pragma unroll
      for (int half = 0; half < 2; ++half) {
        const int oidx = tid + half * 512;
        const int r = oidx >> 8, j = oidx & 255;
        float z0 = part[r*1024 + j]       + part[(4+r)*1024 + j]       + bencS[j];
        float z1 = part[r*1024 + 256 + j] + part[(4+r)*1024 + 256 + j] + bencS[256 + j];
        float z2 = part[r*1024 + 512 + j] + part[(4+r)*1024 + 512 + j] + bencS[512 + j];
        float z3 = part[r*1024 + 768 + j] + part[(4+r)*1024 + 768 + j] + bencS[768 + j];
        float gi = fsig(z0), gf = fsig(z1), gg = fth(z2), go = fsig(z3);
        float cold = hsT[256 + j][r];
        float c2 = fmaf(gf, cold, gi * gg);
        float h2 = go * fth(c2);
        hsT[j][r] = h2;
        hsT[256 + j][r] = c2;
        x1B[(size_t)r * 32768 + step * 256 + j] = h2;
      }
    }
    __syncthreads();
  }
}

// ---------------------------------------------------------------------------
// Decoder + final head: CB/4 blocks * 512 threads, 4 rows per block, 128 steps.
__global__ __launch_bounds__(512) void decoder_k(
    const float* __restrict__ WdT, const float* __restrict__ WhhTd,
    const float* __restrict__ W1T, const float* __restrict__ bdec,
    const float* __restrict__ Vd,  const float* __restrict__ WihD,
    const float* __restrict__ Wt,  const float* __restrict__ btp,
    const float* __restrict__ b1,  const float* __restrict__ W2,
    const float* __restrict__ b2p, const float* __restrict__ yk,
    const float* __restrict__ Udx, const float* __restrict__ x1,
    float* __restrict__ out)
{
  __shared__ __align__(16) float dsT[512][4];   // [d(256); cell(256)] x 4 rows
  __shared__ __align__(16) float cT[256][4];
  __shared__ __align__(16) float part[8192];
  __shared__ float ods[4][256];
  __shared__ float cbuf[4][256];
  __shared__ float betaT[128][4];
  __shared__ float wihdS[1024];
  __shared__ float bdecS[1024];
  __shared__ float yts[4];
  __shared__ float red[8];

  const int tid = threadIdx.x;
  const int b0 = blockIdx.x * 4;

  for (int i = tid; i < 2048; i += 512) ((float*)dsT)[i] = 0.f;
  for (int i = tid; i < 1024; i += 512) { wihdS[i] = WihD[i]; bdecS[i] = bdec[i]; }
  __syncthreads();

  const float bt0 = btp[0];
  const float4* WdT4   = (const float4*)WdT;
  const float4* WhhTd4 = (const float4*)WhhTd;
  const float4* W1T4   = (const float4*)W1T;
  const float4* dsT4   = (const float4*)dsT;
  const float4* cT4    = (const float4*)cT;
  float4* part4 = (float4*)part;

  const int rB = tid >> 7, tB = tid & 127;
  const float4* udxB = (const float4*)Udx + ((size_t)(b0 + rB) * 128 + tB) * 64;
  const float2* x1B2 = (const float2*)x1 + (size_t)(b0 + rB) * 16384;

  for (int step = 0; step < 128; ++step) {
    // --- A: ods[r][kk] = sum_k ds[r][k]*Wd[kk][k], K=512 split 8 ways
    {
      const int l = tid & 63, ks = tid >> 6;
      float4 a0 = {0,0,0,0}, a1 = {0,0,0,0}, a2 = {0,0,0,0}, a3 = {0,0,0,0};
      const int kb = ks * 64;
      #pragma unroll 4
      for (int k = kb; k < kb + 64; ++k) {
        float4 w  = WdT4[k * 64 + l];
        float4 dv = dsT4[k];
        FMA4(a0, dv.x, w); FMA4(a1, dv.y, w); FMA4(a2, dv.z, w); FMA4(a3, dv.w, w);
      }
      part4[(ks * 4 + 0) * 64 + l] = a0;
      part4[(ks * 4 + 1) * 64 + l] = a1;
      part4[(ks * 4 + 2) * 64 + l] = a2;
      part4[(ks * 4 + 3) * 64 + l] = a3;
    }
    __syncthreads();
    {
      #pragma unroll
      for (int half = 0; half < 2; ++half) {
        const int oidx = tid + half * 512;
        const int r = oidx >> 8, kk = oidx & 255;
        float acc = 0.f;
        #pragma unroll
        for (int ks = 0; ks < 8; ++ks) acc += part[(ks * 4 + r) * 256 + kk];
        ods[r][kk] = acc;
      }
    }
    __syncthreads();
    // --- B: l[r][t] = sum_k Vd[k]*tanh(ods[r][k] + Udx[b][t][k])
    float l_val;
    {
      float acc = 0.f;
      #pragma unroll 4
      for (int k4 = 0; k4 < 64; ++k4) {
        float4 u = udxB[k4];
        const int k = k4 * 4;
        acc = fmaf(Vd[k + 0], fth(ods[rB][k + 0] + u.x), acc);
        acc = fmaf(Vd[k + 1], fth(ods[rB][k + 1] + u.y), acc);
        acc = fmaf(Vd[k + 2], fth(ods[rB][k + 2] + u.z), acc);
        acc = fmaf(Vd[k + 3], fth(ods[rB][k + 3] + u.w), acc);
      }
      l_val = acc;
    }
    float mx = rowreduce_max(l_val, red);
    float p  = __expf(l_val - mx);
    float sm = rowreduce_sum(p, red);
    betaT[tB][rB] = p * __builtin_amdgcn_rcpf(sm);
    __syncthreads();
    // --- C: context c[r][m] = sum_t beta[r][t]*x1[b][t][m]
    {
      float2 acc = {0.f, 0.f};
      for (int t = 0; t < 128; ++t) {
        float bv = betaT[t][rB];
        float2 xv = x1B2[t * 128 + tB];
        acc.x = fmaf(bv, xv.x, acc.x);
        acc.y = fmaf(bv, xv.y, acc.y);
      }
      cbuf[rB][2 * tB]     = acc.x;
      cbuf[rB][2 * tB + 1] = acc.y;
      cT[2 * tB][rB]     = acc.x;
      cT[2 * tB + 1][rB] = acc.y;
    }
    __syncthreads();
    // --- D: y_tilde = [y_t, c] @ Wt^T + bt
    {
      float pv = cbuf[rB][tB] * Wt[1 + tB] + cbuf[rB][tB + 128] * Wt[129 + tB];
      float sum = rowreduce_sum(pv, red);
      if ((tid & 127) == 0) {
        yts[rB] = sum + yk[(size_t)(b0 + rB) * 128 + step] * Wt[0] + bt0;
      }
    }
    // --- E: gates z = d @ Whh_d^T (K=256 split 2 ways); rank-1 y_tilde term in update
    {
      const int jl = tid & 255, ks = tid >> 8;
      float4 a0 = {0,0,0,0}, a1 = {0,0,0,0}, a2 = {0,0,0,0}, a3 = {0,0,0,0};
      const int kb = ks * 128;
      for (int k = kb; k < kb + 128; ++k) {
        float4 w  = WhhTd4[k * 256 + jl];
        float4 dv = dsT4[k];
        FMA4(a0, dv.x, w); FMA4(a1, dv.y, w); FMA4(a2, dv.z, w); FMA4(a3, dv.w, w);
      }
      part4[(ks * 4 + 0) * 256 + jl] = a0;
      part4[(ks * 4 + 1) * 256 + jl] = a1;
      part4[(ks * 4 + 2) * 256 + jl] = a2;
      part4[(ks * 4 + 3) * 256 + jl] = a3;
    }
    __syncthreads();
    // --- update
    {
      #pragma unroll
      for (int half = 0; half < 2; ++half) {
        const int oidx = tid + half * 512;
        const int r = oidx >> 8, j = oidx & 255;
        float yt = yts[r];
        float z0 = part[r*1024 + j]       + part[(4+r)*1024 + j]       + fmaf(yt, wihdS[j],       bdecS[j]);
        float z1 = part[r*1024 + 256 + j] + part[(4+r)*1024 + 256 + j] + fmaf(yt, wihdS[256 + j], bdecS[256 + j]);
        float z2 = part[r*1024 + 512 + j] + part[(4+r)*1024 + 512 + j] + fmaf(yt, wihdS[512 + j], bdecS[512 + j]);
        float z3 = part[r*1024 + 768 + j] + part[(4+r)*1024 + 768 + j] + fmaf(yt, wihdS[768 + j], bdecS[768 + j]);
        float gi = fsig(z0), gf = fsig(z1), gg = fth(z2), go = fsig(z3);
        float cold = dsT[256 + j][r];
        float c2 = fmaf(gf, cold, gi * gg);
        float d2 = go * fth(c2);
        dsT[j][r] = d2;
        dsT[256 + j][r] = c2;
      }
    }
    __syncthreads();
  }
  // --- final head: out1 = [d;c] @ W1^T + b1 ; out = out1 @ W2^T + b2
  {
    const int l = tid & 63, ks = tid >> 6;
    float4 a0 = {0,0,0,0}, a1 = {0,0,0,0}, a2 = {0,0,0,0}, a3 = {0,0,0,0};
    const int kb = ks * 64;
    for (int k = kb; k < kb + 64; ++k) {
      float4 w  = W1T4[k * 64 + l];
      float4 dv = (k < 256) ? dsT4[k] : cT4[k - 256];
      FMA4(a0, dv.x, w); FMA4(a1, dv.y, w); FMA4(a2, dv.z, w); FMA4(a3, dv.w, w);
    }
    part4[(ks * 4 + 0) * 64 + l] = a0;
    part4[(ks * 4 + 1) * 64 + l] = a1;
    part4[(ks * 4 + 2) * 64 + l] = a2;
    part4[(ks * 4 + 3) * 64 + l] = a3;
  }
  __syncthreads();
  {
    float o1 = b1[tB], o2 = b1[tB + 128];
    #pragma unroll
    for (int ks = 0; ks < 8; ++ks) {
      o1 += part[(ks * 4 + rB) * 256 + tB];
      o2 += part[(ks * 4 + rB) * 256 + tB + 128];
    }
    float pv = o1 * W2[tB] + o2 * W2[tB + 128];
    float sum = rowreduce_sum(pv, red);
    if ((tid & 127) == 0) out[b0 + rB] = sum + b2p[0];
  }
}

// ---------------------------------------------------------------------------
extern "C" void kernel_launch(void* const* d_in, const int* in_sizes, int n_in,
                              void* d_out, int out_size, void* d_ws, size_t ws_size,
                              hipStream_t stream)
{
  const float* x       = (const float*)d_in[0];
  const float* y_known = (const float*)d_in[1];
  const float* We      = (const float*)d_in[2];
  const float* Ue      = (const float*)d_in[3];
  const float* Ve      = (const float*)d_in[4];
  const float* Wih_e   = (const float*)d_in[5];
  const float* Whh_e   = (const float*)d_in[6];
  const float* bih_e   = (const float*)d_in[7];
  const float* bhh_e   = (const float*)d_in[8];
  const float* Wd      = (const float*)d_in[9];
  const float* Ud      = (const float*)d_in[10];
  const float* Vd      = (const float*)d_in[11];
  const float* Wih_d   = (const float*)d_in[12];
  const float* Whh_d   = (const float*)d_in[13];
  const float* bih_d   = (const float*)d_in[14];
  const float* bhh_d   = (const float*)d_in[15];
  const float* Wt      = (const float*)d_in[16];
  const float* bt      = (const float*)d_in[17];
  const float* W1      = (const float*)d_in[18];
  const float* b1      = (const float*)d_in[19];
  const float* W2      = (const float*)d_in[20];
  const float* b2      = (const float*)d_in[21];

  float* ws  = (float*)d_ws;
  float* out = (float*)d_out;

  // --- adaptive plan: weights + per-chunk [X1: CB*32768][shared UX/UDX: CB*32768]
  int CB = 0;
  for (int cb = 1024; cb >= 4; cb >>= 1) {
    size_t need = 4ull * ((size_t)W_FLOATS + (size_t)cb * 65536ull);
    if (ws_size >= need) { CB = cb; break; }
  }
  if (CB == 0) return;  // < ~5.3 MB scratch: cannot run; visible failure
  const int NC = 1024 / CB;

  float* x1c = ws + W_FLOATS;                       // CB*32768 floats
  float* shc = ws + W_FLOATS + (size_t)CB * 32768;  // CB*32768 floats (UX then UDX)

  prep_k<<<(W_FLOATS + 255) / 256, 256, 0, stream>>>(
      We, Wih_e, Whh_e, Wd, Whh_d, W1, Ud, Ue,
      bih_e, bhh_e, bih_d, bhh_d, ws);

  for (int c = 0; c < NC; ++c) {
    const float* xc  = x + (size_t)c * CB * 16384;
    const float* ykc = y_known + (size_t)c * CB * 128;
    float* outc      = out + (size_t)c * CB;

    ux_k<<<CB * 4, 256, 0, stream>>>(xc, ws + O_UET, shc);
    encoder_k<<<CB / 4, 512, 0, stream>>>(ws + O_WET, ws + O_WENC, ws + O_BENC,
                                          Ve, shc, x1c);
    udx_k<<<CB * 4, 256, 0, stream>>>(x1c, ws + O_UDT, shc);
    decoder_k<<<CB / 4, 512, 0, stream>>>(ws + O_WDT, ws + O_WHHTD, ws + O_W1T,
                                          ws + O_BDEC, Vd, Wih_d, Wt, bt, b1, W2,
                                          b2, ykc, shc, x1c, outc);
  }
}

// Round 3
// 11529.529 us; speedup vs baseline: 3.5917x; 3.5917x over previous
//
#include <hip/hip_runtime.h>

// ---------------------------------------------------------------------------
// DA-RNN forward, full-batch, bf16 streamed arrays (Ux / x1 / Udx), f32 weights.
//   prep_k    : transpose weights + bias sums (f32, 4.27 MB)
//   ux_k      : Ux[b][i][s] bf16 = sum_t x[b,t,i]*Ue[s,t]
//   encoder_k : 128 steps, 4 rows/block, 256 blocks x 512 thr, states in LDS
//   udx_k     : Udx[b][t][k] bf16 = sum_m x1[b,t,m]*Ud[k,m]
//   decoder_k : 128 steps + final head, 4 rows/block, 256 blocks x 512 thr
// ws layout (float slots): [weights 1,067,008][x1h 16,777,216][buf 16,777,216]
//   buf holds Ux during encoder, then Udx (stream-ordered reuse).
// Total = 138,485,760 B == proven available ws floor (round-2 CB=512 fired).
// ---------------------------------------------------------------------------

typedef unsigned int  uint;

#define O_WET     0u
#define O_WENC    65536u       // [384][1024] = [Wih_e^T ; Whh_e^T]
#define O_WDT     458752u      // [512][256]
#define O_WHHTD   589824u      // [256][1024]
#define O_W1T     851968u      // [512][256]
#define O_UDT     983040u      // [256][256]
#define O_UET     1048576u     // [128][128]
#define O_BENC    1064960u
#define O_BDEC    1065984u
#define W_FLOATS  1067008u
#define O_X1H     1067008u     // 33,554,432 bf16 in 16,777,216 float slots
#define O_BUF     17844224u    // Ux (33.5MB) then Udx (67MB) bf16
#define WS_FLOATS 34621440u

#define FMA4(acc, s, w) \
  acc.x = fmaf((s), (w).x, acc.x); \
  acc.y = fmaf((s), (w).y, acc.y); \
  acc.z = fmaf((s), (w).z, acc.z); \
  acc.w = fmaf((s), (w).w, acc.w);

__device__ __forceinline__ float asf(uint u) {
  union { uint i; float f; } v; v.i = u; return v.f;
}
__device__ __forceinline__ uint fbits(float f) {
  union { float f; uint i; } v; v.f = f; return v.i;
}
__device__ __forceinline__ uint rnd_bf(float f) {          // RNE, as u32
  uint u = fbits(f);
  return u + 0x7FFFu + ((u >> 16) & 1u);
}
__device__ __forceinline__ unsigned short f2bf(float f) {
  return (unsigned short)(rnd_bf(f) >> 16);
}
__device__ __forceinline__ uint f2bf2(float lo, float hi) { // pack 2 bf16
  return (rnd_bf(lo) >> 16) | (rnd_bf(hi) & 0xFFFF0000u);
}
#define BLO(w) asf((w) << 16)
#define BHI(w) asf((w) & 0xFFFF0000u)

__device__ __forceinline__ float fsig(float x) {
  return __builtin_amdgcn_rcpf(1.f + __expf(-x));
}
__device__ __forceinline__ float fth(float x) {
  float e2 = __expf(2.f * x);
  return 1.f - 2.f * __builtin_amdgcn_rcpf(e2 + 1.f);
}

// reduce over 128-thread groups (2 waves). ALL threads must call (barriers).
__device__ __forceinline__ float rowreduce_sum(float v, float* red) {
  #pragma unroll
  for (int o = 32; o > 0; o >>= 1) v += __shfl_xor(v, o);
  __syncthreads();
  int w = threadIdx.x >> 6;
  if ((threadIdx.x & 63) == 0) red[w] = v;
  __syncthreads();
  int wb = w & ~1;
  return red[wb] + red[wb + 1];
}
__device__ __forceinline__ float rowreduce_max(float v, float* red) {
  #pragma unroll
  for (int o = 32; o > 0; o >>= 1) v = fmaxf(v, __shfl_xor(v, o));
  __syncthreads();
  int w = threadIdx.x >> 6;
  if ((threadIdx.x & 63) == 0) red[w] = v;
  __syncthreads();
  int wb = w & ~1;
  return fmaxf(red[wb], red[wb + 1]);
}

// ---------------------------------------------------------------------------
__global__ __launch_bounds__(256) void prep_k(
    const float* __restrict__ We,    const float* __restrict__ Wih_e,
    const float* __restrict__ Whh_e, const float* __restrict__ Wd,
    const float* __restrict__ Whh_d, const float* __restrict__ W1,
    const float* __restrict__ Ud,    const float* __restrict__ Ue,
    const float* __restrict__ bih_e, const float* __restrict__ bhh_e,
    const float* __restrict__ bih_d, const float* __restrict__ bhh_d,
    float* __restrict__ ws)
{
  unsigned idx = blockIdx.x * 256u + threadIdx.x;
  if (idx >= W_FLOATS) return;
  if (idx < 65536u) {
    unsigned k = idx >> 7, j = idx & 127u;
    ws[O_WET + idx] = We[j * 512u + k];
  } else if (idx < 196608u) {
    unsigned rel = idx - 65536u;
    unsigned k = rel >> 10, j = rel & 1023u;
    ws[O_WENC + rel] = Wih_e[j * 128u + k];
  } else if (idx < 458752u) {
    unsigned rel = idx - 196608u;
    unsigned k = rel >> 10, j = rel & 1023u;
    ws[O_WENC + 131072u + rel] = Whh_e[j * 256u + k];
  } else if (idx < 589824u) {
    unsigned rel = idx - 458752u;
    unsigned k = rel >> 8, j = rel & 255u;
    ws[O_WDT + rel] = Wd[j * 512u + k];
  } else if (idx < 851968u) {
    unsigned rel = idx - 589824u;
    unsigned k = rel >> 10, j = rel & 1023u;
    ws[O_WHHTD + rel] = Whh_d[j * 256u + k];
  } else if (idx < 983040u) {
    unsigned rel = idx - 851968u;
    unsigned k = rel >> 8, q = rel & 255u;
    ws[O_W1T + rel] = W1[q * 512u + k];
  } else if (idx < 1048576u) {
    unsigned rel = idx - 983040u;
    unsigned m = rel >> 8, k = rel & 255u;
    ws[O_UDT + rel] = Ud[k * 256u + m];
  } else if (idx < 1064960u) {
    unsigned rel = idx - 1048576u;
    unsigned t = rel >> 7, s = rel & 127u;
    ws[O_UET + rel] = Ue[s * 128u + t];
  } else if (idx < 1065984u) {
    unsigned rel = idx - 1064960u;
    ws[O_BENC + rel] = bih_e[rel] + bhh_e[rel];
  } else {
    unsigned rel = idx - 1065984u;
    ws[O_BDEC + rel] = bih_d[rel] + bhh_d[rel];
  }
}

// ---------------------------------------------------------------------------
// Ux[b][i][s] bf16 = sum_t x[b][t][i]*Ue[s][t].  grid = 1024*4.
__global__ __launch_bounds__(256) void ux_k(
    const float* __restrict__ x, const float* __restrict__ UeT,
    uint* __restrict__ Uxh2)     // uint = 2 bf16
{
  __shared__ float xs[128][32];
  const int b  = blockIdx.x >> 2;
  const int i0 = (blockIdx.x & 3) * 32;
  const int tid = threadIdx.x;
  for (int idx = tid; idx < 4096; idx += 256) {
    int t = idx >> 5, il = idx & 31;
    xs[t][il] = x[(size_t)b * 16384 + t * 128 + i0 + il];
  }
  __syncthreads();
  const int sl = tid & 31;
  const int ig = tid >> 5;
  const float4* UeT4 = (const float4*)UeT;
  float4 acc[4];
  #pragma unroll
  for (int ii = 0; ii < 4; ++ii) acc[ii] = make_float4(0.f, 0.f, 0.f, 0.f);
  for (int t = 0; t < 128; ++t) {
    float4 w = UeT4[t * 32 + sl];
    #pragma unroll
    for (int ii = 0; ii < 4; ++ii) {
      float a = xs[t][ig + 8 * ii];
      FMA4(acc[ii], a, w);
    }
  }
  uint2* U2 = (uint2*)Uxh2;   // uint2 = 4 bf16
  #pragma unroll
  for (int ii = 0; ii < 4; ++ii) {
    int i_loc = i0 + ig + 8 * ii;
    uint2 pk;
    pk.x = f2bf2(acc[ii].x, acc[ii].y);
    pk.y = f2bf2(acc[ii].z, acc[ii].w);
    U2[((size_t)b * 128 + i_loc) * 32 + sl] = pk;
  }
}

// ---------------------------------------------------------------------------
// Udx[b][t][k] bf16 = sum_m x1[b][t][m]*Ud[k][m].  grid = 1024*4.
__global__ __launch_bounds__(256) void udx_k(
    const unsigned short* __restrict__ x1h, const float* __restrict__ UdT,
    uint* __restrict__ Udxh2)
{
  __shared__ float xs[32][256];
  const int b  = blockIdx.x >> 2;
  const int t0 = (blockIdx.x & 3) * 32;
  const int tid = threadIdx.x;
  const uint4* x14 = (const uint4*)x1h + (size_t)b * 4096;
  for (int it = 0; it < 4; ++it) {
    int f = tid + it * 256;          // 1024 uint4 total
    int tl = f >> 5, mq = f & 31;
    uint4 u = x14[(size_t)(t0 + tl) * 32 + mq];
    float* d = &xs[tl][mq * 8];
    d[0] = BLO(u.x); d[1] = BHI(u.x); d[2] = BLO(u.y); d[3] = BHI(u.y);
    d[4] = BLO(u.z); d[5] = BHI(u.z); d[6] = BLO(u.w); d[7] = BHI(u.w);
  }
  __syncthreads();
  const int kl = tid & 63;
  const int tg = tid >> 6;
  const float4* UdT4 = (const float4*)UdT;
  float4 acc[8];
  #pragma unroll
  for (int tt = 0; tt < 8; ++tt) acc[tt] = make_float4(0.f, 0.f, 0.f, 0.f);
  for (int m = 0; m < 256; ++m) {
    float4 w = UdT4[m * 64 + kl];
    #pragma unroll
    for (int tt = 0; tt < 8; ++tt) {
      float a = xs[tg + 4 * tt][m];
      FMA4(acc[tt], a, w);
    }
  }
  uint2* U2 = (uint2*)Udxh2;
  #pragma unroll
  for (int tt = 0; tt < 8; ++tt) {
    uint2 pk;
    pk.x = f2bf2(acc[tt].x, acc[tt].y);
    pk.y = f2bf2(acc[tt].z, acc[tt].w);
    U2[((size_t)b * 128 + t0 + tg + 4 * tt) * 64 + kl] = pk;
  }
}

// ---------------------------------------------------------------------------
// Encoder: 256 blocks * 512 threads, 4 rows/block, 128 steps.
__global__ __launch_bounds__(512) void encoder_k(
    const float* __restrict__ WeT, const float* __restrict__ Wenc,
    const float* __restrict__ benc, const float* __restrict__ Ve,
    const unsigned short* __restrict__ Uxh, unsigned short* __restrict__ x1h)
{
  __shared__ __align__(16) float hsT[512][4];   // [h(256);cell(256)] x 4 rows
  __shared__ __align__(16) float part[8192];
  __shared__ float ohs[4][128];
  __shared__ __align__(16) float xtT[128][4];
  __shared__ float bencS[1024];
  __shared__ float VeS[128];
  __shared__ float red[8];

  const int tid = threadIdx.x;
  const int b0 = blockIdx.x * 4;

  for (int i = tid; i < 2048; i += 512) ((float*)hsT)[i] = 0.f;
  for (int i = tid; i < 1024; i += 512) bencS[i] = benc[i];
  if (tid < 128) VeS[tid] = Ve[tid];
  __syncthreads();

  const float4* WeT4  = (const float4*)WeT;
  const float4* Wenc4 = (const float4*)Wenc;
  const float4* hsT4  = (const float4*)hsT;
  const float4* xtT4  = (const float4*)xtT;
  float4* part4 = (float4*)part;

  const int rB = tid >> 7, iB = tid & 127;
  const uint4* ux4 = (const uint4*)Uxh + ((size_t)(b0 + rB) * 128 + iB) * 16;

  for (int step = 0; step < 128; ++step) {
    // --- A: ohs[r][j] = sum_k hs[r][k]*We[j][k], K=512 split 16 ways
    {
      const int l = tid & 31, ks = tid >> 5;
      float4 a0{0,0,0,0}, a1{0,0,0,0}, a2{0,0,0,0}, a3{0,0,0,0};
      const int kb = ks * 32;
      #pragma unroll 4
      for (int k = kb; k < kb + 32; ++k) {
        float4 w  = WeT4[k * 32 + l];
        float4 hv = hsT4[k];
        FMA4(a0, hv.x, w); FMA4(a1, hv.y, w); FMA4(a2, hv.z, w); FMA4(a3, hv.w, w);
      }
      part4[(ks * 4 + 0) * 32 + l] = a0;
      part4[(ks * 4 + 1) * 32 + l] = a1;
      part4[(ks * 4 + 2) * 32 + l] = a2;
      part4[(ks * 4 + 3) * 32 + l] = a3;
    }
    __syncthreads();
    {
      const int r = tid >> 7, j = tid & 127;
      float acc = 0.f;
      #pragma unroll
      for (int ks = 0; ks < 16; ++ks) acc += part[(ks * 4 + r) * 128 + j];
      ohs[r][j] = acc;
    }
    __syncthreads();
    // --- B: e[r][i] = sum_s Ve[s]*tanh(ohs[r][s] + Ux[b][i][s])  (Ux bf16)
    float e_val;
    {
      float a0 = 0.f, a1 = 0.f, a2 = 0.f, a3 = 0.f;
      const float* oh = ohs[rB];
      #pragma unroll 4
      for (int so = 0; so < 16; ++so) {
        uint4 u = ux4[so];
        const int s = so * 8;
        a0 = fmaf(VeS[s + 0], fth(oh[s + 0] + BLO(u.x)), a0);
        a1 = fmaf(VeS[s + 1], fth(oh[s + 1] + BHI(u.x)), a1);
        a2 = fmaf(VeS[s + 2], fth(oh[s + 2] + BLO(u.y)), a2);
        a3 = fmaf(VeS[s + 3], fth(oh[s + 3] + BHI(u.y)), a3);
        a0 = fmaf(VeS[s + 4], fth(oh[s + 4] + BLO(u.z)), a0);
        a1 = fmaf(VeS[s + 5], fth(oh[s + 5] + BHI(u.z)), a1);
        a2 = fmaf(VeS[s + 6], fth(oh[s + 6] + BLO(u.w)), a2);
        a3 = fmaf(VeS[s + 7], fth(oh[s + 7] + BHI(u.w)), a3);
      }
      e_val = (a0 + a1) + (a2 + a3);
    }
    // --- softmax over i, faithful quirk: xt = alpha * e
    float mx = rowreduce_max(e_val, red);
    float p  = __expf(e_val - mx);
    float sm = rowreduce_sum(p, red);
    xtT[iB][rB] = p * __builtin_amdgcn_rcpf(sm) * e_val;
    __syncthreads();
    // --- D: gates z = [xt;h] @ Wenc, K=384 split 2 ways (branchless ranges)
    {
      const int jl = tid & 255, ks = tid >> 8;
      float4 a0{0,0,0,0}, a1{0,0,0,0}, a2{0,0,0,0}, a3{0,0,0,0};
      if (ks == 0) {
        #pragma unroll 2
        for (int k = 0; k < 128; ++k) {
          float4 w  = Wenc4[k * 256 + jl];
          float4 av = xtT4[k];
          FMA4(a0, av.x, w); FMA4(a1, av.y, w); FMA4(a2, av.z, w); FMA4(a3, av.w, w);
        }
        #pragma unroll 2
        for (int k = 128; k < 192; ++k) {
          float4 w  = Wenc4[k * 256 + jl];
          float4 av = hsT4[k - 128];
          FMA4(a0, av.x, w); FMA4(a1, av.y, w); FMA4(a2, av.z, w); FMA4(a3, av.w, w);
        }
      } else {
        #pragma unroll 2
        for (int k = 192; k < 384; ++k) {
          float4 w  = Wenc4[k * 256 + jl];
          float4 av = hsT4[k - 128];
          FMA4(a0, av.x, w); FMA4(a1, av.y, w); FMA4(a2, av.z, w); FMA4(a3, av.w, w);
        }
      }
      part4[(ks * 4 + 0) * 256 + jl] = a0;
      part4[(ks * 4 + 1) * 256 + jl] = a1;
      part4[(ks * 4 + 2) * 256 + jl] = a2;
      part4[(ks * 4 + 3) * 256 + jl] = a3;
    }
    __syncthreads();
    // --- update: gates -> h2,c2; x1 written bf16
    {
      #pragma unroll
      for (int half = 0; half < 2; ++half) {
        const int oidx = tid + half * 512;
        const int r = oidx >> 8, j = oidx & 255;
        float z0 = part[r*1024 + j]       + part[(4+r)*1024 + j]       + bencS[j];
        float z1 = part[r*1024 + 256 + j] + part[(4+r)*1024 + 256 + j] + bencS[256 + j];
        float z2 = part[r*1024 + 512 + j] + part[(4+r)*1024 + 512 + j] + bencS[512 + j];
        float z3 = part[r*1024 + 768 + j] + part[(4+r)*1024 + 768 + j] + bencS[768 + j];
        float gi = fsig(z0), gf = fsig(z1), gg = fth(z2), go = fsig(z3);
        float cold = hsT[256 + j][r];
        float c2 = fmaf(gf, cold, gi * gg);
        float h2 = go * fth(c2);
        hsT[j][r] = h2;
        hsT[256 + j][r] = c2;
        x1h[(size_t)(b0 + r) * 32768 + step * 256 + j] = f2bf(h2);
      }
    }
    __syncthreads();
  }
}

// ---------------------------------------------------------------------------
// Decoder + head: 256 blocks * 512 threads, 4 rows/block, 128 steps.
__global__ __launch_bounds__(512) void decoder_k(
    const float* __restrict__ WdT, const float* __restrict__ WhhTd,
    const float* __restrict__ W1T, const float* __restrict__ bdec,
    const float* __restrict__ Vd,  const float* __restrict__ WihD,
    const float* __restrict__ Wt,  const float* __restrict__ btp,
    const float* __restrict__ b1,  const float* __restrict__ W2,
    const float* __restrict__ b2p, const float* __restrict__ yk,
    const unsigned short* __restrict__ Udxh,
    const unsigned short* __restrict__ x1h,
    float* __restrict__ out)
{
  __shared__ __align__(16) float dsT[512][4];   // [d(256);cell(256)] x 4 rows
  __shared__ __align__(16) float cT[256][4];
  __shared__ __align__(16) float part[8192];
  __shared__ float ods[4][256];
  __shared__ __align__(16) float betaT[128][4];
  __shared__ float wihdS[1024];
  __shared__ float bdecS[1024];
  __shared__ float VdS[256];
  __shared__ float yts[4];
  __shared__ float red[8];

  const int tid = threadIdx.x;
  const int b0 = blockIdx.x * 4;

  for (int i = tid; i < 2048; i += 512) ((float*)dsT)[i] = 0.f;
  for (int i = tid; i < 1024; i += 512) { wihdS[i] = WihD[i]; bdecS[i] = bdec[i]; }
  if (tid < 256) VdS[tid] = Vd[tid];
  __syncthreads();

  const float bt0 = btp[0];
  const float4* WdT4   = (const float4*)WdT;
  const float4* WhhTd4 = (const float4*)WhhTd;
  const float4* W1T4   = (const float4*)W1T;
  const float4* dsT4   = (const float4*)dsT;
  const float4* cT4    = (const float4*)cT;
  float4* part4 = (float4*)part;

  const int rB = tid >> 7, tB = tid & 127;
  const uint4* ud4 = (const uint4*)Udxh + ((size_t)(b0 + rB) * 128 + tB) * 32;
  // phase-C mapping
  const int m8 = tid & 31, rC = (tid >> 5) & 3, ts = tid >> 7;
  const uint4* x14 = (const uint4*)x1h + (size_t)(b0 + rC) * 4096 + m8;

  for (int step = 0; step < 128; ++step) {
    // --- A: ods[r][kk] = sum_k ds[r][k]*Wd[kk][k], K=512 split 8 ways
    {
      const int l = tid & 63, ks = tid >> 6;
      float4 a0{0,0,0,0}, a1{0,0,0,0}, a2{0,0,0,0}, a3{0,0,0,0};
      const int kb = ks * 64;
      #pragma unroll 4
      for (int k = kb; k < kb + 64; ++k) {
        float4 w  = WdT4[k * 64 + l];
        float4 dv = dsT4[k];
        FMA4(a0, dv.x, w); FMA4(a1, dv.y, w); FMA4(a2, dv.z, w); FMA4(a3, dv.w, w);
      }
      part4[(ks * 4 + 0) * 64 + l] = a0;
      part4[(ks * 4 + 1) * 64 + l] = a1;
      part4[(ks * 4 + 2) * 64 + l] = a2;
      part4[(ks * 4 + 3) * 64 + l] = a3;
    }
    __syncthreads();
    {
      #pragma unroll
      for (int half = 0; half < 2; ++half) {
        const int oidx = tid + half * 512;
        const int r = oidx >> 8, kk = oidx & 255;
        float acc = 0.f;
        #pragma unroll
        for (int ks = 0; ks < 8; ++ks) acc += part[(ks * 4 + r) * 256 + kk];
        ods[r][kk] = acc;
      }
    }
    __syncthreads();
    // --- B: l[r][t] = sum_k Vd[k]*tanh(ods[r][k] + Udx[b][t][k])  (bf16)
    float l_val;
    {
      float a0 = 0.f, a1 = 0.f, a2 = 0.f, a3 = 0.f;
      const float* od = ods[rB];
      #pragma unroll 4
      for (int ko = 0; ko < 32; ++ko) {
        uint4 u = ud4[ko];
        const int k = ko * 8;
        a0 = fmaf(VdS[k + 0], fth(od[k + 0] + BLO(u.x)), a0);
        a1 = fmaf(VdS[k + 1], fth(od[k + 1] + BHI(u.x)), a1);
        a2 = fmaf(VdS[k + 2], fth(od[k + 2] + BLO(u.y)), a2);
        a3 = fmaf(VdS[k + 3], fth(od[k + 3] + BHI(u.y)), a3);
        a0 = fmaf(VdS[k + 4], fth(od[k + 4] + BLO(u.z)), a0);
        a1 = fmaf(VdS[k + 5], fth(od[k + 5] + BHI(u.z)), a1);
        a2 = fmaf(VdS[k + 6], fth(od[k + 6] + BLO(u.w)), a2);
        a3 = fmaf(VdS[k + 7], fth(od[k + 7] + BHI(u.w)), a3);
      }
      l_val = (a0 + a1) + (a2 + a3);
    }
    float mx = rowreduce_max(l_val, red);
    float p  = __expf(l_val - mx);
    float sm = rowreduce_sum(p, red);
    betaT[tB][rB] = p * __builtin_amdgcn_rcpf(sm);
    __syncthreads();
    // --- C: c[r][m] = sum_t beta[r][t]*x1[b][t][m]  (bf16, 4-way t-split)
    {
      float c0=0,c1=0,c2=0,c3=0,c4=0,c5=0,c6=0,c7=0;
      #pragma unroll 4
      for (int tt = 0; tt < 32; ++tt) {
        const int t = ts * 32 + tt;
        float bv = betaT[t][rC];
        uint4 u = x14[(size_t)t * 32];
        c0 = fmaf(bv, BLO(u.x), c0);
        c1 = fmaf(bv, BHI(u.x), c1);
        c2 = fmaf(bv, BLO(u.y), c2);
        c3 = fmaf(bv, BHI(u.y), c3);
        c4 = fmaf(bv, BLO(u.z), c4);
        c5 = fmaf(bv, BHI(u.z), c5);
        c6 = fmaf(bv, BLO(u.w), c6);
        c7 = fmaf(bv, BHI(u.w), c7);
      }
      float4* pc = part4 + ts * 256 + rC * 64 + m8 * 2;
      pc[0] = make_float4(c0, c1, c2, c3);
      pc[1] = make_float4(c4, c5, c6, c7);
    }
    __syncthreads();
    {
      #pragma unroll
      for (int half = 0; half < 2; ++half) {
        const int o = tid + half * 512;
        const int r = o >> 8, m = o & 255;
        float v = part[o] + part[1024 + o] + part[2048 + o] + part[3072 + o];
        cT[m][r] = v;
      }
    }
    __syncthreads();
    // --- D: y_tilde = [y_t, c] @ Wt^T + bt
    {
      float pv = cT[tB][rB] * Wt[1 + tB] + cT[tB + 128][rB] * Wt[129 + tB];
      float sum = rowreduce_sum(pv, red);
      if ((tid & 127) == 0) {
        yts[rB] = sum + yk[(size_t)(b0 + rB) * 128 + step] * Wt[0] + bt0;
      }
    }
    // --- E: gates z = d @ Whh_d^T, K=256 split 2 ways
    {
      const int jl = tid & 255, ks = tid >> 8;
      float4 a0{0,0,0,0}, a1{0,0,0,0}, a2{0,0,0,0}, a3{0,0,0,0};
      const int kb = ks * 128;
      #pragma unroll 2
      for (int k = kb; k < kb + 128; ++k) {
        float4 w  = WhhTd4[k * 256 + jl];
        float4 dv = dsT4[k];
        FMA4(a0, dv.x, w); FMA4(a1, dv.y, w); FMA4(a2, dv.z, w); FMA4(a3, dv.w, w);
      }
      part4[(ks * 4 + 0) * 256 + jl] = a0;
      part4[(ks * 4 + 1) * 256 + jl] = a1;
      part4[(ks * 4 + 2) * 256 + jl] = a2;
      part4[(ks * 4 + 3) * 256 + jl] = a3;
    }
    __syncthreads();
    // --- update
    {
      #pragma unroll
      for (int half = 0; half < 2; ++half) {
        const int oidx = tid + half * 512;
        const int r = oidx >> 8, j = oidx & 255;
        float yt = yts[r];
        float z0 = part[r*1024 + j]       + part[(4+r)*1024 + j]       + fmaf(yt, wihdS[j],       bdecS[j]);
        float z1 = part[r*1024 + 256 + j] + part[(4+r)*1024 + 256 + j] + fmaf(yt, wihdS[256 + j], bdecS[256 + j]);
        float z2 = part[r*1024 + 512 + j] + part[(4+r)*1024 + 512 + j] + fmaf(yt, wihdS[512 + j], bdecS[512 + j]);
        float z3 = part[r*1024 + 768 + j] + part[(4+r)*1024 + 768 + j] + fmaf(yt, wihdS[768 + j], bdecS[768 + j]);
        float gi = fsig(z0), gf = fsig(z1), gg = fth(z2), go = fsig(z3);
        float cold = dsT[256 + j][r];
        float c2 = fmaf(gf, cold, gi * gg);
        float d2 = go * fth(c2);
        dsT[j][r] = d2;
        dsT[256 + j][r] = c2;
      }
    }
    __syncthreads();
  }
  // --- final head: out1 = [d;c] @ W1^T + b1 ; out = out1 @ W2^T + b2
  {
    const int l = tid & 63, ks = tid >> 6;
    float4 a0{0,0,0,0}, a1{0,0,0,0}, a2{0,0,0,0}, a3{0,0,0,0};
    const int kb = ks * 64;
    for (int k = kb; k < kb + 64; ++k) {
      float4 w  = W1T4[k * 64 + l];
      float4 dv = (k < 256) ? dsT4[k] : cT4[k - 256];
      FMA4(a0, dv.x, w); FMA4(a1, dv.y, w); FMA4(a2, dv.z, w); FMA4(a3, dv.w, w);
    }
    part4[(ks * 4 + 0) * 64 + l] = a0;
    part4[(ks * 4 + 1) * 64 + l] = a1;
    part4[(ks * 4 + 2) * 64 + l] = a2;
    part4[(ks * 4 + 3) * 64 + l] = a3;
  }
  __syncthreads();
  {
    const int rB2 = tid >> 7, tB2 = tid & 127;
    float o1 = b1[tB2], o2 = b1[tB2 + 128];
    #pragma unroll
    for (int ks = 0; ks < 8; ++ks) {
      o1 += part[(ks * 4 + rB2) * 256 + tB2];
      o2 += part[(ks * 4 + rB2) * 256 + tB2 + 128];
    }
    float pv = o1 * W2[tB2] + o2 * W2[tB2 + 128];
    float sum = rowreduce_sum(pv, red);
    if ((tid & 127) == 0) out[b0 + rB2] = sum + b2p[0];
  }
}

// ---------------------------------------------------------------------------
extern "C" void kernel_launch(void* const* d_in, const int* in_sizes, int n_in,
                              void* d_out, int out_size, void* d_ws, size_t ws_size,
                              hipStream_t stream)
{
  const float* x       = (const float*)d_in[0];
  const float* y_known = (const float*)d_in[1];
  const float* We      = (const float*)d_in[2];
  const float* Ue      = (const float*)d_in[3];
  const float* Ve      = (const float*)d_in[4];
  const float* Wih_e   = (const float*)d_in[5];
  const float* Whh_e   = (const float*)d_in[6];
  const float* bih_e   = (const float*)d_in[7];
  const float* bhh_e   = (const float*)d_in[8];
  const float* Wd      = (const float*)d_in[9];
  const float* Ud      = (const float*)d_in[10];
  const float* Vd      = (const float*)d_in[11];
  const float* Wih_d   = (const float*)d_in[12];
  const float* Whh_d   = (const float*)d_in[13];
  const float* bih_d   = (const float*)d_in[14];
  const float* bhh_d   = (const float*)d_in[15];
  const float* Wt      = (const float*)d_in[16];
  const float* bt      = (const float*)d_in[17];
  const float* W1      = (const float*)d_in[18];
  const float* b1      = (const float*)d_in[19];
  const float* W2      = (const float*)d_in[20];
  const float* b2      = (const float*)d_in[21];

  float* ws  = (float*)d_ws;
  float* out = (float*)d_out;
  if (ws_size < (size_t)WS_FLOATS * 4u) return;  // 138,485,760 B == proven floor

  unsigned short* x1h  = (unsigned short*)(ws + O_X1H);
  unsigned short* bufh = (unsigned short*)(ws + O_BUF);  // Ux, then Udx

  prep_k<<<(W_FLOATS + 255) / 256, 256, 0, stream>>>(
      We, Wih_e, Whh_e, Wd, Whh_d, W1, Ud, Ue,
      bih_e, bhh_e, bih_d, bhh_d, ws);

  ux_k<<<4096, 256, 0, stream>>>(x, ws + O_UET, (uint*)bufh);
  encoder_k<<<256, 512, 0, stream>>>(ws + O_WET, ws + O_WENC, ws + O_BENC, Ve,
                                     bufh, x1h);
  udx_k<<<4096, 256, 0, stream>>>(x1h, ws + O_UDT, (uint*)bufh);
  decoder_k<<<256, 512, 0, stream>>>(ws + O_WDT, ws + O_WHHTD, ws + O_W1T,
                                     ws + O_BDEC, Vd, Wih_d, Wt, bt, b1, W2, b2,
                                     y_known, bufh, x1h, out);
}

// Round 4
// 8813.112 us; speedup vs baseline: 4.6988x; 1.3082x over previous
//
#include <hip/hip_runtime.h>

// ---------------------------------------------------------------------------
// DA-RNN forward. Round 4: 2 rows/block (512 blocks x 512 thr = 2 blocks/CU,
// 16 waves/CU) + bf16-packed streamed weights (WeT/Wenc/WdT/WhhTd) to halve
// per-XCD L2 weight bandwidth. States/biases/Ve/Vd/head weights stay f32.
// Streamed activations (Ux/x1/Udx) bf16 as in round 3.
// ws (float slots): packed weights/biases 641,024 | x1h 16,777,216 | buf 16,777,216
// Total 136,781,824 B <= proven floor 138,485,760 B.
// ---------------------------------------------------------------------------

typedef unsigned int   uint;
typedef unsigned short ushort;

#define O_WETH    0u          // [512][64]  uints: We^T j-pairs
#define O_WENCH   32768u      // [384][512] uints: [Wih_e^T;Whh_e^T] col-pairs
#define O_WDTH    229376u     // [512][128] uints: Wd^T col-pairs
#define O_WHHTDH  294912u     // [256][512] uints: Whh_d^T col-pairs
#define O_UDT     425984u     // [256][256] f32
#define O_UET     491520u     // [128][128] f32
#define O_W1T     507904u     // [512][256] f32
#define O_BENC    638976u
#define O_BDEC    640000u
#define W_FLOATS  641024u
#define O_X1H     641024u     // x1 bf16 [1024][128][256]
#define O_BUF     17418240u   // Ux bf16 (8.4M slots) then Udx bf16 (16.7M slots)
#define WS_FLOATS 34195456u

#define FMA4(acc, s, w) \
  acc.x = fmaf((s), (w).x, acc.x); \
  acc.y = fmaf((s), (w).y, acc.y); \
  acc.z = fmaf((s), (w).z, acc.z); \
  acc.w = fmaf((s), (w).w, acc.w);

__device__ __forceinline__ float asf(uint u) {
  union { uint i; float f; } v; v.i = u; return v.f;
}
__device__ __forceinline__ uint fbits(float f) {
  union { float f; uint i; } v; v.f = f; return v.i;
}
__device__ __forceinline__ uint rnd_bf(float f) {          // RNE
  uint u = fbits(f);
  return u + 0x7FFFu + ((u >> 16) & 1u);
}
__device__ __forceinline__ ushort f2bf(float f) {
  return (ushort)(rnd_bf(f) >> 16);
}
__device__ __forceinline__ uint f2bf2(float lo, float hi) {
  return (rnd_bf(lo) >> 16) | (rnd_bf(hi) & 0xFFFF0000u);
}
#define BLO(w) asf((w) << 16)
#define BHI(w) asf((w) & 0xFFFF0000u)

// unpack uint4 (8 bf16 weights) and FMA into two row-accumulators
#define UPK_FMA2(w, h0, h1, a, b) { \
  float w0=BLO(w.x),w1=BHI(w.x),w2=BLO(w.y),w3=BHI(w.y); \
  float w4=BLO(w.z),w5=BHI(w.z),w6=BLO(w.w),w7=BHI(w.w); \
  a[0]=fmaf(h0,w0,a[0]); a[1]=fmaf(h0,w1,a[1]); a[2]=fmaf(h0,w2,a[2]); a[3]=fmaf(h0,w3,a[3]); \
  a[4]=fmaf(h0,w4,a[4]); a[5]=fmaf(h0,w5,a[5]); a[6]=fmaf(h0,w6,a[6]); a[7]=fmaf(h0,w7,a[7]); \
  b[0]=fmaf(h1,w0,b[0]); b[1]=fmaf(h1,w1,b[1]); b[2]=fmaf(h1,w2,b[2]); b[3]=fmaf(h1,w3,b[3]); \
  b[4]=fmaf(h1,w4,b[4]); b[5]=fmaf(h1,w5,b[5]); b[6]=fmaf(h1,w6,b[6]); b[7]=fmaf(h1,w7,b[7]); }

#define UPK_FMA1(u, s, c) { \
  c[0]=fmaf(s,BLO(u.x),c[0]); c[1]=fmaf(s,BHI(u.x),c[1]); \
  c[2]=fmaf(s,BLO(u.y),c[2]); c[3]=fmaf(s,BHI(u.y),c[3]); \
  c[4]=fmaf(s,BLO(u.z),c[4]); c[5]=fmaf(s,BHI(u.z),c[5]); \
  c[6]=fmaf(s,BLO(u.w),c[6]); c[7]=fmaf(s,BHI(u.w),c[7]); }

__device__ __forceinline__ float fsig(float x) {
  return __builtin_amdgcn_rcpf(1.f + __expf(-x));
}
__device__ __forceinline__ float fth(float x) {
  float e2 = __expf(2.f * x);
  return 1.f - 2.f * __builtin_amdgcn_rcpf(e2 + 1.f);
}

// reduce over 256-thread groups (4 waves). ALL 512 threads must call.
__device__ __forceinline__ float grp4_sum(float v, float* red) {
  #pragma unroll
  for (int o = 32; o > 0; o >>= 1) v += __shfl_xor(v, o);
  __syncthreads();
  int w = threadIdx.x >> 6;
  if ((threadIdx.x & 63) == 0) red[w] = v;
  __syncthreads();
  int wb = w & 4;
  return (red[wb] + red[wb + 1]) + (red[wb + 2] + red[wb + 3]);
}
__device__ __forceinline__ float grp4_max(float v, float* red) {
  #pragma unroll
  for (int o = 32; o > 0; o >>= 1) v = fmaxf(v, __shfl_xor(v, o));
  __syncthreads();
  int w = threadIdx.x >> 6;
  if ((threadIdx.x & 63) == 0) red[w] = v;
  __syncthreads();
  int wb = w & 4;
  return fmaxf(fmaxf(red[wb], red[wb + 1]), fmaxf(red[wb + 2], red[wb + 3]));
}

// ---------------------------------------------------------------------------
__global__ __launch_bounds__(256) void prep_k(
    const float* __restrict__ We,    const float* __restrict__ Wih_e,
    const float* __restrict__ Whh_e, const float* __restrict__ Wd,
    const float* __restrict__ Whh_d, const float* __restrict__ W1,
    const float* __restrict__ Ud,    const float* __restrict__ Ue,
    const float* __restrict__ bih_e, const float* __restrict__ bhh_e,
    const float* __restrict__ bih_d, const float* __restrict__ bhh_d,
    float* __restrict__ ws)
{
  uint* wsu = (uint*)ws;
  unsigned idx = blockIdx.x * 256u + threadIdx.x;
  if (idx >= W_FLOATS) return;
  if (idx < 229376u) {
    if (idx < 32768u) {                       // WeTh[k][jp]
      unsigned k = idx >> 6, jp = idx & 63u;
      wsu[O_WETH + idx] = f2bf2(We[(2u*jp) * 512u + k], We[(2u*jp + 1u) * 512u + k]);
    } else {                                  // Wench[k][jgp]
      unsigned rel = idx - 32768u;
      unsigned k = rel >> 9, jgp = rel & 511u;
      unsigned jg0 = 2u * jgp, jg1 = jg0 + 1u;
      float v0, v1;
      if (k < 128u) { v0 = Wih_e[jg0 * 128u + k];        v1 = Wih_e[jg1 * 128u + k]; }
      else          { v0 = Whh_e[jg0 * 256u + k - 128u]; v1 = Whh_e[jg1 * 256u + k - 128u]; }
      wsu[O_WENCH + rel] = f2bf2(v0, v1);
    }
  } else if (idx < 294912u) {                 // WdTh[k][kkp]
    unsigned rel = idx - 229376u;
    unsigned k = rel >> 7, kkp = rel & 127u;
    wsu[O_WDTH + rel] = f2bf2(Wd[(2u*kkp) * 512u + k], Wd[(2u*kkp + 1u) * 512u + k]);
  } else if (idx < 425984u) {                 // WhhTdh[k][jgp]
    unsigned rel = idx - 294912u;
    unsigned k = rel >> 9, jgp = rel & 511u;
    wsu[O_WHHTDH + rel] = f2bf2(Whh_d[(2u*jgp) * 256u + k], Whh_d[(2u*jgp + 1u) * 256u + k]);
  } else if (idx < 491520u) {                 // UdT[m][k]
    unsigned rel = idx - 425984u;
    unsigned m = rel >> 8, k = rel & 255u;
    ws[O_UDT + rel] = Ud[k * 256u + m];
  } else if (idx < 507904u) {                 // UeT[t][s]
    unsigned rel = idx - 491520u;
    unsigned t = rel >> 7, s = rel & 127u;
    ws[O_UET + rel] = Ue[s * 128u + t];
  } else if (idx < 638976u) {                 // W1T[k][q]
    unsigned rel = idx - 507904u;
    unsigned k = rel >> 8, q = rel & 255u;
    ws[O_W1T + rel] = W1[q * 512u + k];
  } else if (idx < 640000u) {
    unsigned rel = idx - 638976u;
    ws[O_BENC + rel] = bih_e[rel] + bhh_e[rel];
  } else {
    unsigned rel = idx - 640000u;
    ws[O_BDEC + rel] = bih_d[rel] + bhh_d[rel];
  }
}

// ---------------------------------------------------------------------------
// Ux[b][i][s] bf16 = sum_t x[b][t][i]*Ue[s][t].  grid = 1024*4.
__global__ __launch_bounds__(256) void ux_k(
    const float* __restrict__ x, const float* __restrict__ UeT,
    uint* __restrict__ Uxh2)
{
  __shared__ float xs[128][32];
  const int b  = blockIdx.x >> 2;
  const int i0 = (blockIdx.x & 3) * 32;
  const int tid = threadIdx.x;
  for (int idx = tid; idx < 4096; idx += 256) {
    int t = idx >> 5, il = idx & 31;
    xs[t][il] = x[(size_t)b * 16384 + t * 128 + i0 + il];
  }
  __syncthreads();
  const int sl = tid & 31;
  const int ig = tid >> 5;
  const float4* UeT4 = (const float4*)UeT;
  float4 acc[4];
  #pragma unroll
  for (int ii = 0; ii < 4; ++ii) acc[ii] = make_float4(0.f, 0.f, 0.f, 0.f);
  for (int t = 0; t < 128; ++t) {
    float4 w = UeT4[t * 32 + sl];
    #pragma unroll
    for (int ii = 0; ii < 4; ++ii) {
      float a = xs[t][ig + 8 * ii];
      FMA4(acc[ii], a, w);
    }
  }
  uint2* U2 = (uint2*)Uxh2;
  #pragma unroll
  for (int ii = 0; ii < 4; ++ii) {
    int i_loc = i0 + ig + 8 * ii;
    uint2 pk;
    pk.x = f2bf2(acc[ii].x, acc[ii].y);
    pk.y = f2bf2(acc[ii].z, acc[ii].w);
    U2[((size_t)b * 128 + i_loc) * 32 + sl] = pk;
  }
}

// ---------------------------------------------------------------------------
// Udx[b][t][k] bf16 = sum_m x1[b][t][m]*Ud[k][m].  grid = 1024*4.
__global__ __launch_bounds__(256) void udx_k(
    const ushort* __restrict__ x1h, const float* __restrict__ UdT,
    uint* __restrict__ Udxh2)
{
  __shared__ float xs[32][256];
  const int b  = blockIdx.x >> 2;
  const int t0 = (blockIdx.x & 3) * 32;
  const int tid = threadIdx.x;
  const uint4* x14 = (const uint4*)x1h + (size_t)b * 4096;
  for (int it = 0; it < 4; ++it) {
    int f = tid + it * 256;
    int tl = f >> 5, mq = f & 31;
    uint4 u = x14[(size_t)(t0 + tl) * 32 + mq];
    float* d = &xs[tl][mq * 8];
    d[0] = BLO(u.x); d[1] = BHI(u.x); d[2] = BLO(u.y); d[3] = BHI(u.y);
    d[4] = BLO(u.z); d[5] = BHI(u.z); d[6] = BLO(u.w); d[7] = BHI(u.w);
  }
  __syncthreads();
  const int kl = tid & 63;
  const int tg = tid >> 6;
  const float4* UdT4 = (const float4*)UdT;
  float4 acc[8];
  #pragma unroll
  for (int tt = 0; tt < 8; ++tt) acc[tt] = make_float4(0.f, 0.f, 0.f, 0.f);
  for (int m = 0; m < 256; ++m) {
    float4 w = UdT4[m * 64 + kl];
    #pragma unroll
    for (int tt = 0; tt < 8; ++tt) {
      float a = xs[tg + 4 * tt][m];
      FMA4(acc[tt], a, w);
    }
  }
  uint2* U2 = (uint2*)Udxh2;
  #pragma unroll
  for (int tt = 0; tt < 8; ++tt) {
    uint2 pk;
    pk.x = f2bf2(acc[tt].x, acc[tt].y);
    pk.y = f2bf2(acc[tt].z, acc[tt].w);
    U2[((size_t)b * 128 + t0 + tg + 4 * tt) * 64 + kl] = pk;
  }
}

// ---------------------------------------------------------------------------
// Encoder: 512 blocks * 512 threads, 2 rows/block (2 blocks/CU), 128 steps.
__global__ __launch_bounds__(512, 4) void encoder_k(
    const uint* __restrict__ WeTh, const uint* __restrict__ Wench,
    const float* __restrict__ benc, const float* __restrict__ Ve,
    const ushort* __restrict__ Uxh, ushort* __restrict__ x1h)
{
  __shared__ float hsT[512][2];       // [h(256);cell(256)] x 2 rows
  __shared__ __align__(16) float part[8192];
  __shared__ float ohs[2][128];
  __shared__ float xtT[128][2];
  __shared__ float bencS[1024];
  __shared__ float VeS[128];
  __shared__ float red[8];

  const int tid = threadIdx.x;
  const int b0 = blockIdx.x * 2;

  for (int i = tid; i < 1024; i += 512) { ((float*)hsT)[i] = 0.f; bencS[i] = benc[i]; }
  for (int i = tid + 512; i < 1024; i += 512) bencS[i] = benc[i];
  if (tid < 128) VeS[tid] = Ve[tid];
  __syncthreads();

  const uint4* WeTh4  = (const uint4*)WeTh;    // row k: 16 uint4
  const uint4* Wench4 = (const uint4*)Wench;   // row k: 128 uint4
  float4* part4 = (float4*)part;

  const int rB = tid >> 8, iB = (tid >> 1) & 127, sh = tid & 1;
  const uint4* ux4 = (const uint4*)Uxh + ((size_t)(b0 + rB) * 128 + iB) * 16 + sh * 8;

  for (int step = 0; step < 128; ++step) {
    // --- A: ohs[r][j] = sum_k hs[r][k]*We[j][k], 32 ksplits x 16 k
    {
      const int jl = tid & 15, ks = tid >> 4;
      float a[8], b[8];
      #pragma unroll
      for (int e = 0; e < 8; ++e) { a[e] = 0.f; b[e] = 0.f; }
      const int kb = ks * 16;
      #pragma unroll 4
      for (int k = kb; k < kb + 16; ++k) {
        uint4 w = WeTh4[k * 16 + jl];
        float h0 = hsT[k][0], h1 = hsT[k][1];
        UPK_FMA2(w, h0, h1, a, b);
      }
      part4[(ks * 2 + 0) * 32 + jl * 2]     = make_float4(a[0], a[1], a[2], a[3]);
      part4[(ks * 2 + 0) * 32 + jl * 2 + 1] = make_float4(a[4], a[5], a[6], a[7]);
      part4[(ks * 2 + 1) * 32 + jl * 2]     = make_float4(b[0], b[1], b[2], b[3]);
      part4[(ks * 2 + 1) * 32 + jl * 2 + 1] = make_float4(b[4], b[5], b[6], b[7]);
    }
    __syncthreads();
    if (tid < 256) {
      const int r = tid >> 7, j = tid & 127;
      float acc = 0.f;
      #pragma unroll
      for (int ks = 0; ks < 32; ++ks) acc += part[(ks * 2 + r) * 128 + j];
      ohs[r][j] = acc;
    }
    __syncthreads();
    // --- B: e[r][i] = sum_s Ve[s]*tanh(ohs[r][s]+Ux[b][i][s]), s split by sh
    float e_val;
    {
      float a0 = 0.f, a1 = 0.f, a2 = 0.f, a3 = 0.f;
      const float* oh = ohs[rB];
      #pragma unroll 2
      for (int so = 0; so < 8; ++so) {
        uint4 u = ux4[so];
        const int s = sh * 64 + so * 8;
        a0 = fmaf(VeS[s + 0], fth(oh[s + 0] + BLO(u.x)), a0);
        a1 = fmaf(VeS[s + 1], fth(oh[s + 1] + BHI(u.x)), a1);
        a2 = fmaf(VeS[s + 2], fth(oh[s + 2] + BLO(u.y)), a2);
        a3 = fmaf(VeS[s + 3], fth(oh[s + 3] + BHI(u.y)), a3);
        a0 = fmaf(VeS[s + 4], fth(oh[s + 4] + BLO(u.z)), a0);
        a1 = fmaf(VeS[s + 5], fth(oh[s + 5] + BHI(u.z)), a1);
        a2 = fmaf(VeS[s + 6], fth(oh[s + 6] + BLO(u.w)), a2);
        a3 = fmaf(VeS[s + 7], fth(oh[s + 7] + BHI(u.w)), a3);
      }
      e_val = (a0 + a1) + (a2 + a3);
      e_val += __shfl_xor(e_val, 1);          // combine the two s-halves
    }
    float mx = grp4_max(e_val, red);
    float p  = __expf(e_val - mx);
    float sm = grp4_sum(sh == 0 ? p : 0.f, red);
    if (sh == 0) xtT[iB][rB] = p * __builtin_amdgcn_rcpf(sm) * e_val;  // alpha*e quirk
    __syncthreads();
    // --- D: gates = [xt;h] @ Wenc, 4 ksplits x 96 k
    {
      const int jl = tid & 127, ks = tid >> 7;
      float a[8], b[8];
      #pragma unroll
      for (int e = 0; e < 8; ++e) { a[e] = 0.f; b[e] = 0.f; }
      const int k0 = ks * 96;
      const int kx_end = (k0 + 96 < 128) ? k0 + 96 : 128;
      #pragma unroll 2
      for (int k = k0; k < kx_end; ++k) {
        uint4 w = Wench4[k * 128 + jl];
        float x0 = xtT[k][0], x1v = xtT[k][1];
        UPK_FMA2(w, x0, x1v, a, b);
      }
      const int kh0 = (k0 > 128) ? k0 : 128;
      #pragma unroll 2
      for (int k = kh0; k < k0 + 96; ++k) {
        uint4 w = Wench4[k * 128 + jl];
        float h0 = hsT[k - 128][0], h1 = hsT[k - 128][1];
        UPK_FMA2(w, h0, h1, a, b);
      }
      part4[(ks * 2 + 0) * 256 + jl * 2]     = make_float4(a[0], a[1], a[2], a[3]);
      part4[(ks * 2 + 0) * 256 + jl * 2 + 1] = make_float4(a[4], a[5], a[6], a[7]);
      part4[(ks * 2 + 1) * 256 + jl * 2]     = make_float4(b[0], b[1], b[2], b[3]);
      part4[(ks * 2 + 1) * 256 + jl * 2 + 1] = make_float4(b[4], b[5], b[6], b[7]);
    }
    __syncthreads();
    // --- update
    {
      const int r = tid >> 8, j = tid & 255;
      float z[4];
      #pragma unroll
      for (int g = 0; g < 4; ++g) {
        const int jg = g * 256 + j;
        float z_ = bencS[jg];
        #pragma unroll
        for (int ks = 0; ks < 4; ++ks) z_ += part[(ks * 2 + r) * 1024 + jg];
        z[g] = z_;
      }
      float gi = fsig(z[0]), gf = fsig(z[1]), gg = fth(z[2]), go = fsig(z[3]);
      float cold = hsT[256 + j][r];
      float c2 = fmaf(gf, cold, gi * gg);
      float h2 = go * fth(c2);
      hsT[j][r] = h2;
      hsT[256 + j][r] = c2;
      x1h[(size_t)(b0 + r) * 32768 + step * 256 + j] = f2bf(h2);
    }
    __syncthreads();
  }
}

// ---------------------------------------------------------------------------
// Decoder + head: 512 blocks * 512 threads, 2 rows/block, 128 steps.
__global__ __launch_bounds__(512, 4) void decoder_k(
    const uint* __restrict__ WdTh, const uint* __restrict__ WhhTdh,
    const float* __restrict__ W1T, const float* __restrict__ bdec,
    const float* __restrict__ Vd,  const float* __restrict__ WihD,
    const float* __restrict__ Wt,  const float* __restrict__ btp,
    const float* __restrict__ b1,  const float* __restrict__ W2,
    const float* __restrict__ b2p, const float* __restrict__ yk,
    const ushort* __restrict__ Udxh, const ushort* __restrict__ x1h,
    float* __restrict__ out)
{
  __shared__ float dsT[512][2];       // [d(256);cell(256)] x 2 rows
  __shared__ float cT[256][2];
  __shared__ __align__(16) float part[8192];
  __shared__ float ods[2][256];
  __shared__ float betaT[128][2];
  __shared__ float wihdS[1024];
  __shared__ float bdecS[1024];
  __shared__ float VdS[256];
  __shared__ float yts[2];
  __shared__ float red[8];

  const int tid = threadIdx.x;
  const int b0 = blockIdx.x * 2;

  for (int i = tid; i < 1024; i += 512) {
    ((float*)dsT)[i] = 0.f;
    wihdS[i] = WihD[i]; bdecS[i] = bdec[i];
  }
  for (int i = tid + 512; i < 1024; i += 512) { wihdS[i] = WihD[i]; bdecS[i] = bdec[i]; }
  if (tid < 256) VdS[tid] = Vd[tid];
  __syncthreads();

  const float bt0 = btp[0];
  const uint4*  WdTh4   = (const uint4*)WdTh;     // row k: 32 uint4
  const uint4*  WhhTdh4 = (const uint4*)WhhTdh;   // row k: 128 uint4
  const float4* W1T4    = (const float4*)W1T;
  float4* part4 = (float4*)part;

  const int rB = tid >> 8, tB = (tid >> 1) & 127, kh = tid & 1;
  const uint4* ud4 = (const uint4*)Udxh + ((size_t)(b0 + rB) * 128 + tB) * 32 + kh * 16;
  const int m8 = tid & 31, rb2 = (tid >> 5) & 1, ts = tid >> 6;
  const uint4* x14 = (const uint4*)x1h + (size_t)(b0 + rb2) * 4096 + m8;

  for (int step = 0; step < 128; ++step) {
    // --- A: ods[r][kk] = sum_k ds[r][k]*Wd[kk][k], 16 ksplits x 32 k
    {
      const int kkl = tid & 31, ks = tid >> 5;
      float a[8], b[8];
      #pragma unroll
      for (int e = 0; e < 8; ++e) { a[e] = 0.f; b[e] = 0.f; }
      const int kb = ks * 32;
      #pragma unroll 4
      for (int k = kb; k < kb + 32; ++k) {
        uint4 w = WdTh4[k * 32 + kkl];
        float d0 = dsT[k][0], d1 = dsT[k][1];
        UPK_FMA2(w, d0, d1, a, b);
      }
      part4[(ks * 2 + 0) * 64 + kkl * 2]     = make_float4(a[0], a[1], a[2], a[3]);
      part4[(ks * 2 + 0) * 64 + kkl * 2 + 1] = make_float4(a[4], a[5], a[6], a[7]);
      part4[(ks * 2 + 1) * 64 + kkl * 2]     = make_float4(b[0], b[1], b[2], b[3]);
      part4[(ks * 2 + 1) * 64 + kkl * 2 + 1] = make_float4(b[4], b[5], b[6], b[7]);
    }
    __syncthreads();
    {
      const int r = tid >> 8, kk = tid & 255;
      float acc = 0.f;
      #pragma unroll
      for (int ks = 0; ks < 16; ++ks) acc += part[(ks * 2 + r) * 256 + kk];
      ods[r][kk] = acc;
    }
    __syncthreads();
    // --- B: l[r][t] = sum_k Vd[k]*tanh(ods[r][k]+Udx[b][t][k]), k split by kh
    float l_val;
    {
      float a0 = 0.f, a1 = 0.f, a2 = 0.f, a3 = 0.f;
      const float* od = ods[rB];
      #pragma unroll 2
      for (int ko = 0; ko < 16; ++ko) {
        uint4 u = ud4[ko];
        const int k = kh * 128 + ko * 8;
        a0 = fmaf(VdS[k + 0], fth(od[k + 0] + BLO(u.x)), a0);
        a1 = fmaf(VdS[k + 1], fth(od[k + 1] + BHI(u.x)), a1);
        a2 = fmaf(VdS[k + 2], fth(od[k + 2] + BLO(u.y)), a2);
        a3 = fmaf(VdS[k + 3], fth(od[k + 3] + BHI(u.y)), a3);
        a0 = fmaf(VdS[k + 4], fth(od[k + 4] + BLO(u.z)), a0);
        a1 = fmaf(VdS[k + 5], fth(od[k + 5] + BHI(u.z)), a1);
        a2 = fmaf(VdS[k + 6], fth(od[k + 6] + BLO(u.w)), a2);
        a3 = fmaf(VdS[k + 7], fth(od[k + 7] + BHI(u.w)), a3);
      }
      l_val = (a0 + a1) + (a2 + a3);
      l_val += __shfl_xor(l_val, 1);
    }
    float mx = grp4_max(l_val, red);
    float p  = __expf(l_val - mx);
    float sm = grp4_sum(kh == 0 ? p : 0.f, red);
    if (kh == 0) betaT[tB][rB] = p * __builtin_amdgcn_rcpf(sm);
    __syncthreads();
    // --- C: c[r][m] = sum_t beta[r][t]*x1[b][t][m], 8 tsplits x 16 t
    {
      float c[8];
      #pragma unroll
      for (int e = 0; e < 8; ++e) c[e] = 0.f;
      #pragma unroll 4
      for (int tt = 0; tt < 16; ++tt) {
        const int t = ts * 16 + tt;
        float bv = betaT[t][rb2];
        uint4 u = x14[(size_t)t * 32];
        UPK_FMA1(u, bv, c);
      }
      part4[(ts * 2 + rb2) * 64 + m8 * 2]     = make_float4(c[0], c[1], c[2], c[3]);
      part4[(ts * 2 + rb2) * 64 + m8 * 2 + 1] = make_float4(c[4], c[5], c[6], c[7]);
    }
    __syncthreads();
    {
      const int r = tid >> 8, m = tid & 255;
      float v = 0.f;
      #pragma unroll
      for (int t8 = 0; t8 < 8; ++t8) v += part[(t8 * 2 + r) * 256 + m];
      cT[m][r] = v;
    }
    __syncthreads();
    // --- D: y_tilde = [y_t, c] @ Wt^T + bt
    {
      const int r = tid >> 8, i = tid & 255;
      float pv = cT[i][r] * Wt[1 + i];
      float sum = grp4_sum(pv, red);
      if ((tid & 255) == 0) {
        yts[r] = sum + yk[(size_t)(b0 + r) * 128 + step] * Wt[0] + bt0;
      }
    }
    // --- E: gates = d @ Whh_d^T, 4 ksplits x 64 k
    {
      const int jl = tid & 127, ks = tid >> 7;
      float a[8], b[8];
      #pragma unroll
      for (int e = 0; e < 8; ++e) { a[e] = 0.f; b[e] = 0.f; }
      const int kb = ks * 64;
      #pragma unroll 2
      for (int k = kb; k < kb + 64; ++k) {
        uint4 w = WhhTdh4[k * 128 + jl];
        float d0 = dsT[k][0], d1 = dsT[k][1];
        UPK_FMA2(w, d0, d1, a, b);
      }
      part4[(ks * 2 + 0) * 256 + jl * 2]     = make_float4(a[0], a[1], a[2], a[3]);
      part4[(ks * 2 + 0) * 256 + jl * 2 + 1] = make_float4(a[4], a[5], a[6], a[7]);
      part4[(ks * 2 + 1) * 256 + jl * 2]     = make_float4(b[0], b[1], b[2], b[3]);
      part4[(ks * 2 + 1) * 256 + jl * 2 + 1] = make_float4(b[4], b[5], b[6], b[7]);
    }
    __syncthreads();
    // --- update
    {
      const int r = tid >> 8, j = tid & 255;
      float yt = yts[r];
      float z[4];
      #pragma unroll
      for (int g = 0; g < 4; ++g) {
        const int jg = g * 256 + j;
        float z_ = fmaf(yt, wihdS[jg], bdecS[jg]);
        #pragma unroll
        for (int ks = 0; ks < 4; ++ks) z_ += part[(ks * 2 + r) * 1024 + jg];
        z[g] = z_;
      }
      float gi = fsig(z[0]), gf = fsig(z[1]), gg = fth(z[2]), go = fsig(z[3]);
      float cold = dsT[256 + j][r];
      float c2 = fmaf(gf, cold, gi * gg);
      float d2 = go * fth(c2);
      dsT[j][r] = d2;
      dsT[256 + j][r] = c2;
    }
    __syncthreads();
  }
  // --- final head: out1 = [d;c] @ W1^T + b1 ; out = out1 @ W2^T + b2
  {
    const int l = tid & 63, ks = tid >> 6;   // 8 ksplits x 64 k
    float a[4], b[4];
    #pragma unroll
    for (int e = 0; e < 4; ++e) { a[e] = 0.f; b[e] = 0.f; }
    const int kb = ks * 64;
    if (ks < 4) {
      for (int k = kb; k < kb + 64; ++k) {
        float4 w = W1T4[k * 64 + l];
        float d0 = dsT[k][0], d1 = dsT[k][1];
        a[0]=fmaf(d0,w.x,a[0]); a[1]=fmaf(d0,w.y,a[1]); a[2]=fmaf(d0,w.z,a[2]); a[3]=fmaf(d0,w.w,a[3]);
        b[0]=fmaf(d1,w.x,b[0]); b[1]=fmaf(d1,w.y,b[1]); b[2]=fmaf(d1,w.z,b[2]); b[3]=fmaf(d1,w.w,b[3]);
      }
    } else {
      for (int k = kb; k < kb + 64; ++k) {
        float4 w = W1T4[k * 64 + l];
        float c0 = cT[k - 256][0], c1 = cT[k - 256][1];
        a[0]=fmaf(c0,w.x,a[0]); a[1]=fmaf(c0,w.y,a[1]); a[2]=fmaf(c0,w.z,a[2]); a[3]=fmaf(c0,w.w,a[3]);
        b[0]=fmaf(c1,w.x,b[0]); b[1]=fmaf(c1,w.y,b[1]); b[2]=fmaf(c1,w.z,b[2]); b[3]=fmaf(c1,w.w,b[3]);
      }
    }
    part4[(ks * 2 + 0) * 64 + l] = make_float4(a[0], a[1], a[2], a[3]);
    part4[(ks * 2 + 1) * 64 + l] = make_float4(b[0], b[1], b[2], b[3]);
  }
  __syncthreads();
  {
    const int r = tid >> 8, q = tid & 255;
    float o1 = b1[q];
    #pragma unroll
    for (int ks = 0; ks < 8; ++ks) o1 += part[(ks * 2 + r) * 256 + q];
    float pv = o1 * W2[q];
    float sum = grp4_sum(pv, red);
    if ((tid & 255) == 0) out[b0 + r] = sum + b2p[0];
  }
}

// ---------------------------------------------------------------------------
extern "C" void kernel_launch(void* const* d_in, const int* in_sizes, int n_in,
                              void* d_out, int out_size, void* d_ws, size_t ws_size,
                              hipStream_t stream)
{
  const float* x       = (const float*)d_in[0];
  const float* y_known = (const float*)d_in[1];
  const float* We      = (const float*)d_in[2];
  const float* Ue      = (const float*)d_in[3];
  const float* Ve      = (const float*)d_in[4];
  const float* Wih_e   = (const float*)d_in[5];
  const float* Whh_e   = (const float*)d_in[6];
  const float* bih_e   = (const float*)d_in[7];
  const float* bhh_e   = (const float*)d_in[8];
  const float* Wd      = (const float*)d_in[9];
  const float* Ud      = (const float*)d_in[10];
  const float* Vd      = (const float*)d_in[11];
  const float* Wih_d   = (const float*)d_in[12];
  const float* Whh_d   = (const float*)d_in[13];
  const float* bih_d   = (const float*)d_in[14];
  const float* bhh_d   = (const float*)d_in[15];
  const float* Wt      = (const float*)d_in[16];
  const float* bt      = (const float*)d_in[17];
  const float* W1      = (const float*)d_in[18];
  const float* b1      = (const float*)d_in[19];
  const float* W2      = (const float*)d_in[20];
  const float* b2      = (const float*)d_in[21];

  float* ws  = (float*)d_ws;
  float* out = (float*)d_out;
  if (ws_size < (size_t)WS_FLOATS * 4u) return;  // 136.8 MB <= proven floor

  uint*   wsu  = (uint*)ws;
  ushort* x1h  = (ushort*)(ws + O_X1H);
  ushort* bufh = (ushort*)(ws + O_BUF);   // Ux, then Udx

  prep_k<<<(W_FLOATS + 255) / 256, 256, 0, stream>>>(
      We, Wih_e, Whh_e, Wd, Whh_d, W1, Ud, Ue,
      bih_e, bhh_e, bih_d, bhh_d, ws);

  ux_k<<<4096, 256, 0, stream>>>(x, ws + O_UET, (uint*)bufh);
  encoder_k<<<512, 512, 0, stream>>>(wsu + O_WETH, wsu + O_WENCH,
                                     ws + O_BENC, Ve, bufh, x1h);
  udx_k<<<4096, 256, 0, stream>>>(x1h, ws + O_UDT, (uint*)bufh);
  decoder_k<<<512, 512, 0, stream>>>(wsu + O_WDTH, wsu + O_WHHTDH,
                                     ws + O_W1T, ws + O_BDEC, Vd, Wih_d,
                                     Wt, bt, b1, W2, b2, y_known,
                                     bufh, x1h, out);
}

// Round 5
// 7280.535 us; speedup vs baseline: 5.6879x; 1.2105x over previous
//
#include <hip/hip_runtime.h>

// ---------------------------------------------------------------------------
// DA-RNN forward, round 5: f16 dot2 GEMMs.
//   - Streamed weights packed as f16 (k,k+1) pairs; inner loops use
//     v_dot2_f32_f16 (2 FMA / slot, no unpack).
//   - LSTM h/c states: f32 recurrence in registers (cell) + packed-f16 pair
//     array in LDS (GEMM input), built with shfl_down + even-lane writes.
//   - Ux / x1 / Udx streams in f16.
//   - Attention tanh: e = SVe - 2*Sum Ve*rcp(1+exp2(C2E*(oh+u))), C2E*oh hoisted.
// ws (float slots): weights 641,024 | x1h 16,777,216 | buf 16,777,216
// Total 136,781,824 B <= proven floor.
// ---------------------------------------------------------------------------

typedef unsigned int   uint;
typedef unsigned short ushort;
typedef _Float16 h2v __attribute__((ext_vector_type(2)));

#define O_WEH     0u          // [256 kp][128 j]  uints (We^T f16 kpairs)
#define O_WENCH   32768u      // [192 kp][1024 j] uints ([Wih_e;Whh_e]^T)
#define O_WDH     229376u     // [256 kp][256 kk] uints (Wd^T)
#define O_WHHDH   294912u     // [128 kp][1024 j] uints (Whh_d^T)
#define O_UDT     425984u     // [256][256] f32
#define O_UET     491520u     // [128][128] f32
#define O_W1T     507904u     // [512][256] f32
#define O_BENC    638976u
#define O_BDEC    640000u
#define W_FLOATS  641024u
#define O_X1H     641024u     // x1 f16 [1024][128][128 pair-uints]
#define O_BUF     17418240u   // Ux f16, then Udx f16
#define WS_FLOATS 34195456u

#define C2E 2.8853900817779268f   // 2*log2(e)
#define L2E 1.4426950408889634f   // log2(e)

#define FMA4(acc, s, w) \
  acc.x = fmaf((s), (w).x, acc.x); \
  acc.y = fmaf((s), (w).y, acc.y); \
  acc.z = fmaf((s), (w).z, acc.z); \
  acc.w = fmaf((s), (w).w, acc.w);

union H2U { uint u; h2v h; _Float16 hs[2]; };

__device__ __forceinline__ float fdot2u(uint w, uint s, float acc) {
  H2U a; a.u = w; H2U b; b.u = s;
  return __builtin_amdgcn_fdot2(a.h, b.h, acc, false);
}
__device__ __forceinline__ uint pk2(float lo, float hi) {   // RNE f16 pair
  H2U v; v.hs[0] = (_Float16)lo; v.hs[1] = (_Float16)hi; return v.u;
}
__device__ __forceinline__ float h2lo(uint u) { H2U v; v.u = u; return (float)v.hs[0]; }
__device__ __forceinline__ float h2hi(uint u) { H2U v; v.u = u; return (float)v.hs[1]; }

__device__ __forceinline__ float fsig(float x) {   // 1/(1+e^-x)
  return __builtin_amdgcn_rcpf(1.f + __builtin_amdgcn_exp2f(-L2E * x));
}
__device__ __forceinline__ float fth(float x) {    // tanh
  float r = __builtin_amdgcn_rcpf(1.f + __builtin_amdgcn_exp2f(C2E * x));
  return fmaf(-2.f, r, 1.f);
}

// reduce over 256-thread groups (4 waves). ALL 512 threads must call.
__device__ __forceinline__ float grp4_sum(float v, float* red) {
  #pragma unroll
  for (int o = 32; o > 0; o >>= 1) v += __shfl_xor(v, o);
  __syncthreads();
  int w = threadIdx.x >> 6;
  if ((threadIdx.x & 63) == 0) red[w] = v;
  __syncthreads();
  int wb = w & 4;
  return (red[wb] + red[wb + 1]) + (red[wb + 2] + red[wb + 3]);
}
__device__ __forceinline__ float grp4_max(float v, float* red) {
  #pragma unroll
  for (int o = 32; o > 0; o >>= 1) v = fmaxf(v, __shfl_xor(v, o));
  __syncthreads();
  int w = threadIdx.x >> 6;
  if ((threadIdx.x & 63) == 0) red[w] = v;
  __syncthreads();
  int wb = w & 4;
  return fmaxf(fmaxf(red[wb], red[wb + 1]), fmaxf(red[wb + 2], red[wb + 3]));
}

// ---------------------------------------------------------------------------
__global__ __launch_bounds__(256) void prep_k(
    const float* __restrict__ We,    const float* __restrict__ Wih_e,
    const float* __restrict__ Whh_e, const float* __restrict__ Wd,
    const float* __restrict__ Whh_d, const float* __restrict__ W1,
    const float* __restrict__ Ud,    const float* __restrict__ Ue,
    const float* __restrict__ bih_e, const float* __restrict__ bhh_e,
    const float* __restrict__ bih_d, const float* __restrict__ bhh_d,
    float* __restrict__ ws)
{
  uint* wsu = (uint*)ws;
  unsigned idx = blockIdx.x * 256u + threadIdx.x;
  if (idx >= W_FLOATS) return;
  if (idx < 32768u) {                         // WeH[kp][j]
    unsigned kp = idx >> 7, j = idx & 127u;
    wsu[O_WEH + idx] = pk2(We[j * 512u + 2u*kp], We[j * 512u + 2u*kp + 1u]);
  } else if (idx < 229376u) {                 // WencH[kp][j]
    unsigned rel = idx - 32768u;
    unsigned kp = rel >> 10, j = rel & 1023u;
    float v0, v1;
    if (kp < 64u) { v0 = Wih_e[j * 128u + 2u*kp];          v1 = Wih_e[j * 128u + 2u*kp + 1u]; }
    else { unsigned k0 = 2u*(kp - 64u); v0 = Whh_e[j * 256u + k0]; v1 = Whh_e[j * 256u + k0 + 1u]; }
    wsu[O_WENCH + rel] = pk2(v0, v1);
  } else if (idx < 294912u) {                 // WdH[kp][kk]
    unsigned rel = idx - 229376u;
    unsigned kp = rel >> 8, kk = rel & 255u;
    wsu[O_WDH + rel] = pk2(Wd[kk * 512u + 2u*kp], Wd[kk * 512u + 2u*kp + 1u]);
  } else if (idx < 425984u) {                 // WhhdH[kp][j]
    unsigned rel = idx - 294912u;
    unsigned kp = rel >> 10, j = rel & 1023u;
    wsu[O_WHHDH + rel] = pk2(Whh_d[j * 256u + 2u*kp], Whh_d[j * 256u + 2u*kp + 1u]);
  } else if (idx < 491520u) {                 // UdT[m][k]
    unsigned rel = idx - 425984u;
    unsigned m = rel >> 8, k = rel & 255u;
    ws[O_UDT + rel] = Ud[k * 256u + m];
  } else if (idx < 507904u) {                 // UeT[t][s]
    unsigned rel = idx - 491520u;
    unsigned t = rel >> 7, s = rel & 127u;
    ws[O_UET + rel] = Ue[s * 128u + t];
  } else if (idx < 638976u) {                 // W1T[k][q]
    unsigned rel = idx - 507904u;
    unsigned k = rel >> 8, q = rel & 255u;
    ws[O_W1T + rel] = W1[q * 512u + k];
  } else if (idx < 640000u) {
    unsigned rel = idx - 638976u;
    ws[O_BENC + rel] = bih_e[rel] + bhh_e[rel];
  } else {
    unsigned rel = idx - 640000u;
    ws[O_BDEC + rel] = bih_d[rel] + bhh_d[rel];
  }
}

// ---------------------------------------------------------------------------
// Ux[b][i][s] f16 = sum_t x[b][t][i]*Ue[s][t].  grid = 1024*4.
__global__ __launch_bounds__(256) void ux_k(
    const float* __restrict__ x, const float* __restrict__ UeT,
    uint* __restrict__ UxU)
{
  __shared__ float xs[128][32];
  const int b  = blockIdx.x >> 2;
  const int i0 = (blockIdx.x & 3) * 32;
  const int tid = threadIdx.x;
  for (int idx = tid; idx < 4096; idx += 256) {
    int t = idx >> 5, il = idx & 31;
    xs[t][il] = x[(size_t)b * 16384 + t * 128 + i0 + il];
  }
  __syncthreads();
  const int sl = tid & 31;
  const int ig = tid >> 5;
  const float4* UeT4 = (const float4*)UeT;
  float4 acc[4];
  #pragma unroll
  for (int ii = 0; ii < 4; ++ii) acc[ii] = make_float4(0.f, 0.f, 0.f, 0.f);
  for (int t = 0; t < 128; ++t) {
    float4 w = UeT4[t * 32 + sl];
    #pragma unroll
    for (int ii = 0; ii < 4; ++ii) {
      float a = xs[t][ig + 8 * ii];
      FMA4(acc[ii], a, w);
    }
  }
  uint2* U2 = (uint2*)UxU;
  #pragma unroll
  for (int ii = 0; ii < 4; ++ii) {
    int i_loc = i0 + ig + 8 * ii;
    uint2 pk;
    pk.x = pk2(acc[ii].x, acc[ii].y);
    pk.y = pk2(acc[ii].z, acc[ii].w);
    U2[((size_t)b * 128 + i_loc) * 32 + sl] = pk;
  }
}

// ---------------------------------------------------------------------------
// Udx[b][t][k] f16 = sum_m x1[b][t][m]*Ud[k][m].  grid = 1024*4.
__global__ __launch_bounds__(256) void udx_k(
    const uint* __restrict__ x1hU, const float* __restrict__ UdT,
    uint* __restrict__ UdxU)
{
  __shared__ float xs[32][256];
  const int b  = blockIdx.x >> 2;
  const int t0 = (blockIdx.x & 3) * 32;
  const int tid = threadIdx.x;
  const uint4* x14 = (const uint4*)x1hU + (size_t)b * 4096;
  for (int it = 0; it < 4; ++it) {
    int f = tid + it * 256;
    int tl = f >> 5, mq = f & 31;
    uint4 u = x14[(size_t)(t0 + tl) * 32 + mq];
    float* d = &xs[tl][mq * 8];
    d[0] = h2lo(u.x); d[1] = h2hi(u.x); d[2] = h2lo(u.y); d[3] = h2hi(u.y);
    d[4] = h2lo(u.z); d[5] = h2hi(u.z); d[6] = h2lo(u.w); d[7] = h2hi(u.w);
  }
  __syncthreads();
  const int kl = tid & 63;
  const int tg = tid >> 6;
  const float4* UdT4 = (const float4*)UdT;
  float4 acc[8];
  #pragma unroll
  for (int tt = 0; tt < 8; ++tt) acc[tt] = make_float4(0.f, 0.f, 0.f, 0.f);
  for (int m = 0; m < 256; ++m) {
    float4 w = UdT4[m * 64 + kl];
    #pragma unroll
    for (int tt = 0; tt < 8; ++tt) {
      float a = xs[tg + 4 * tt][m];
      FMA4(acc[tt], a, w);
    }
  }
  uint2* U2 = (uint2*)UdxU;
  #pragma unroll
  for (int tt = 0; tt < 8; ++tt) {
    uint2 pk;
    pk.x = pk2(acc[tt].x, acc[tt].y);
    pk.y = pk2(acc[tt].z, acc[tt].w);
    U2[((size_t)b * 128 + t0 + tg + 4 * tt) * 64 + kl] = pk;
  }
}

// ---------------------------------------------------------------------------
// Encoder: 512 blocks * 512 threads, 2 rows/block, 128 steps, dot2 GEMMs.
__global__ __launch_bounds__(512, 4) void encoder_k(
    const uint* __restrict__ WeH, const uint* __restrict__ WencH,
    const float* __restrict__ benc, const float* __restrict__ Ve,
    const uint* __restrict__ UxH, uint* __restrict__ x1hU)
{
  __shared__ uint stH[2][256];          // [h-pairs 0..127 | c-pairs 128..255]
  __shared__ uint xtH[2][64];
  __shared__ __align__(16) float part[4096];
  __shared__ float ohs2[2][128];        // C2E * ohs
  __shared__ float xtT[128][2];
  __shared__ float bencS[1024];
  __shared__ float VeS[128];
  __shared__ float red[8];

  const int tid = threadIdx.x;
  const int b0 = blockIdx.x * 2;

  ((uint*)stH)[tid] = 0u;
  for (int i = tid; i < 1024; i += 512) bencS[i] = benc[i];
  if (tid < 128) VeS[tid] = Ve[tid];
  __syncthreads();

  float SVe = 0.f;
  #pragma unroll 8
  for (int s = 0; s < 128; ++s) SVe += VeS[s];

  const uint4* WeH4   = (const uint4*)WeH;     // row kp: 32 uint4
  const uint4* WencH4 = (const uint4*)WencH;   // row kp: 256 uint4
  float4* part4 = (float4*)part;

  const int rB = tid >> 8, iB = (tid >> 1) & 127, sh = tid & 1;
  const uint4* ux4 = (const uint4*)UxH + ((size_t)(b0 + rB) * 128 + iB) * 16 + sh * 8;

  float c_reg = 0.f;                    // cell state for (r=tid>>8, j=tid&255)

  for (int step = 0; step < 128; ++step) {
    // --- A: ohs[r][j] = sum_k hs[r][k]*We[j][k]; 16 ksplits x 16 kpairs
    {
      const int j4 = tid & 31, ks = tid >> 5;
      float a0=0,a1=0,a2=0,a3=0,b0=0,b1=0,b2=0,b3=0;
      const int kb = ks * 16;
      #pragma unroll 4
      for (int kp = kb; kp < kb + 16; ++kp) {
        uint4 w = WeH4[kp * 32 + j4];
        uint s0 = stH[0][kp], s1 = stH[1][kp];
        a0 = fdot2u(w.x, s0, a0); a1 = fdot2u(w.y, s0, a1);
        a2 = fdot2u(w.z, s0, a2); a3 = fdot2u(w.w, s0, a3);
        b0 = fdot2u(w.x, s1, b0); b1 = fdot2u(w.y, s1, b1);
        b2 = fdot2u(w.z, s1, b2); b3 = fdot2u(w.w, s1, b3);
      }
      part4[(ks * 2 + 0) * 32 + j4] = make_float4(a0, a1, a2, a3);
      part4[(ks * 2 + 1) * 32 + j4] = make_float4(b0, b1, b2, b3);
    }
    __syncthreads();
    if (tid < 256) {
      const int r = tid >> 7, j = tid & 127;
      float acc = 0.f;
      #pragma unroll
      for (int ks = 0; ks < 16; ++ks) acc += part[(ks * 2 + r) * 128 + j];
      ohs2[r][j] = acc * C2E;
    }
    __syncthreads();
    // --- B: e[r][i] = SVe - 2*sum_s Ve[s]*rcp(1+exp2(C2E*u + ohs2[s]))
    float e_val;
    {
      float a0 = 0.f, a1 = 0.f, a2 = 0.f, a3 = 0.f;
      const float* oh = ohs2[rB];
      #pragma unroll 2
      for (int so = 0; so < 8; ++so) {
        uint4 u = ux4[so];
        const int s = sh * 64 + so * 8;
        a0 = fmaf(VeS[s+0], __builtin_amdgcn_rcpf(1.f + __builtin_amdgcn_exp2f(fmaf(C2E, h2lo(u.x), oh[s+0]))), a0);
        a1 = fmaf(VeS[s+1], __builtin_amdgcn_rcpf(1.f + __builtin_amdgcn_exp2f(fmaf(C2E, h2hi(u.x), oh[s+1]))), a1);
        a2 = fmaf(VeS[s+2], __builtin_amdgcn_rcpf(1.f + __builtin_amdgcn_exp2f(fmaf(C2E, h2lo(u.y), oh[s+2]))), a2);
        a3 = fmaf(VeS[s+3], __builtin_amdgcn_rcpf(1.f + __builtin_amdgcn_exp2f(fmaf(C2E, h2hi(u.y), oh[s+3]))), a3);
        a0 = fmaf(VeS[s+4], __builtin_amdgcn_rcpf(1.f + __builtin_amdgcn_exp2f(fmaf(C2E, h2lo(u.z), oh[s+4]))), a0);
        a1 = fmaf(VeS[s+5], __builtin_amdgcn_rcpf(1.f + __builtin_amdgcn_exp2f(fmaf(C2E, h2hi(u.z), oh[s+5]))), a1);
        a2 = fmaf(VeS[s+6], __builtin_amdgcn_rcpf(1.f + __builtin_amdgcn_exp2f(fmaf(C2E, h2lo(u.w), oh[s+6]))), a2);
        a3 = fmaf(VeS[s+7], __builtin_amdgcn_rcpf(1.f + __builtin_amdgcn_exp2f(fmaf(C2E, h2hi(u.w), oh[s+7]))), a3);
      }
      float r4 = (a0 + a1) + (a2 + a3);
      r4 += __shfl_xor(r4, 1);
      e_val = fmaf(-2.f, r4, SVe);
    }
    // --- softmax over i; faithful quirk xt = alpha*e
    float mx = grp4_max(e_val, red);
    float p  = __builtin_amdgcn_exp2f(L2E * (e_val - mx));
    float sm = grp4_sum(sh == 0 ? p : 0.f, red);
    if (sh == 0) xtT[iB][rB] = p * __builtin_amdgcn_rcpf(sm) * e_val;
    __syncthreads();
    if (tid < 128) {                    // pack xt into f16 pairs
      const int r = tid >> 6, ii = tid & 63;
      xtH[r][ii] = pk2(xtT[2 * ii][r], xtT[2 * ii + 1][r]);
    }
    __syncthreads();
    // --- D: gates = [xt;h] @ Wenc; 2 ksplits x 96 kpairs
    {
      const int j4 = tid & 255, ks = tid >> 8;
      float a0=0,a1=0,a2=0,a3=0,b0=0,b1=0,b2=0,b3=0;
      if (ks == 0) {
        #pragma unroll 2
        for (int kp = 0; kp < 64; ++kp) {
          uint4 w = WencH4[kp * 256 + j4];
          uint s0 = xtH[0][kp], s1 = xtH[1][kp];
          a0 = fdot2u(w.x, s0, a0); a1 = fdot2u(w.y, s0, a1);
          a2 = fdot2u(w.z, s0, a2); a3 = fdot2u(w.w, s0, a3);
          b0 = fdot2u(w.x, s1, b0); b1 = fdot2u(w.y, s1, b1);
          b2 = fdot2u(w.z, s1, b2); b3 = fdot2u(w.w, s1, b3);
        }
        #pragma unroll 2
        for (int kp = 64; kp < 96; ++kp) {
          uint4 w = WencH4[kp * 256 + j4];
          uint s0 = stH[0][kp - 64], s1 = stH[1][kp - 64];
          a0 = fdot2u(w.x, s0, a0); a1 = fdot2u(w.y, s0, a1);
          a2 = fdot2u(w.z, s0, a2); a3 = fdot2u(w.w, s0, a3);
          b0 = fdot2u(w.x, s1, b0); b1 = fdot2u(w.y, s1, b1);
          b2 = fdot2u(w.z, s1, b2); b3 = fdot2u(w.w, s1, b3);
        }
      } else {
        #pragma unroll 2
        for (int kp = 96; kp < 192; ++kp) {
          uint4 w = WencH4[kp * 256 + j4];
          uint s0 = stH[0][kp - 64], s1 = stH[1][kp - 64];
          a0 = fdot2u(w.x, s0, a0); a1 = fdot2u(w.y, s0, a1);
          a2 = fdot2u(w.z, s0, a2); a3 = fdot2u(w.w, s0, a3);
          b0 = fdot2u(w.x, s1, b0); b1 = fdot2u(w.y, s1, b1);
          b2 = fdot2u(w.z, s1, b2); b3 = fdot2u(w.w, s1, b3);
        }
      }
      part4[(ks * 2 + 0) * 256 + j4] = make_float4(a0, a1, a2, a3);
      part4[(ks * 2 + 1) * 256 + j4] = make_float4(b0, b1, b2, b3);
    }
    __syncthreads();
    // --- update: gates -> h2,c2 (cell in register); pack pairs via shfl
    {
      const int r = tid >> 8, j = tid & 255;
      float z0 = bencS[j]       + part[r * 1024 + j]       + part[(2 + r) * 1024 + j];
      float z1 = bencS[256 + j] + part[r * 1024 + 256 + j] + part[(2 + r) * 1024 + 256 + j];
      float z2 = bencS[512 + j] + part[r * 1024 + 512 + j] + part[(2 + r) * 1024 + 512 + j];
      float z3 = bencS[768 + j] + part[r * 1024 + 768 + j] + part[(2 + r) * 1024 + 768 + j];
      float gi = fsig(z0), gf = fsig(z1), gg = fth(z2), go = fsig(z3);
      float c2 = fmaf(gf, c_reg, gi * gg);
      c_reg = c2;
      float h2 = go * fth(c2);
      float hn = __shfl_down(h2, 1);
      float cn = __shfl_down(c2, 1);
      if (!(j & 1)) {
        uint hp = pk2(h2, hn), cp = pk2(c2, cn);
        stH[r][j >> 1] = hp;
        stH[r][128 + (j >> 1)] = cp;
        x1hU[((size_t)(b0 + r) * 128 + step) * 128 + (j >> 1)] = hp;
      }
    }
    __syncthreads();
  }
}

// ---------------------------------------------------------------------------
// Decoder + head: 512 blocks * 512 threads, 2 rows/block, 128 steps.
__global__ __launch_bounds__(512, 4) void decoder_k(
    const uint* __restrict__ WdH, const uint* __restrict__ WhhdH,
    const float* __restrict__ W1T, const float* __restrict__ bdec,
    const float* __restrict__ Vd,  const float* __restrict__ WihD,
    const float* __restrict__ Wt,  const float* __restrict__ btp,
    const float* __restrict__ b1,  const float* __restrict__ W2,
    const float* __restrict__ b2p, const float* __restrict__ yk,
    const uint* __restrict__ UdxH, const uint* __restrict__ x1hU,
    float* __restrict__ out)
{
  __shared__ uint stH[2][256];          // [d-pairs 0..127 | c-pairs 128..255]
  __shared__ __align__(16) float part[4096];
  __shared__ float ods2[2][256];        // C2E * ods
  __shared__ float cT[256][2];
  __shared__ float betaT[128][2];
  __shared__ float wihdS[1024];
  __shared__ float bdecS[1024];
  __shared__ float VdS[256];
  __shared__ float yts[2];
  __shared__ float red[8];

  const int tid = threadIdx.x;
  const int b0 = blockIdx.x * 2;

  ((uint*)stH)[tid] = 0u;
  for (int i = tid; i < 1024; i += 512) { wihdS[i] = WihD[i]; bdecS[i] = bdec[i]; }
  if (tid < 256) VdS[tid] = Vd[tid];
  __syncthreads();

  float SVd = 0.f;
  #pragma unroll 8
  for (int k = 0; k < 256; ++k) SVd += VdS[k];

  const float bt0 = btp[0];
  const uint4*  WdH4   = (const uint4*)WdH;     // row kp: 64 uint4
  const uint4*  WhhdH4 = (const uint4*)WhhdH;   // row kp: 256 uint4
  const float4* W1T4   = (const float4*)W1T;
  float4* part4 = (float4*)part;

  const int rB = tid >> 8, tB = (tid >> 1) & 127, kh = tid & 1;
  const uint4* ud4 = (const uint4*)UdxH + ((size_t)(b0 + rB) * 128 + tB) * 32 + kh * 16;
  const int m8 = tid & 31, rb2 = (tid >> 5) & 1, ts = tid >> 6;
  const uint4* x14 = (const uint4*)x1hU + (size_t)(b0 + rb2) * 4096 + m8;

  float c_reg = 0.f;

  for (int step = 0; step < 128; ++step) {
    // --- A: ods[r][kk] = sum_k ds[r][k]*Wd[kk][k]; 8 ksplits x 32 kpairs
    {
      const int j4 = tid & 63, ks = tid >> 6;
      float a0=0,a1=0,a2=0,a3=0,b0=0,b1=0,b2=0,b3=0;
      const int kb = ks * 32;
      #pragma unroll 4
      for (int kp = kb; kp < kb + 32; ++kp) {
        uint4 w = WdH4[kp * 64 + j4];
        uint s0 = stH[0][kp], s1 = stH[1][kp];
        a0 = fdot2u(w.x, s0, a0); a1 = fdot2u(w.y, s0, a1);
        a2 = fdot2u(w.z, s0, a2); a3 = fdot2u(w.w, s0, a3);
        b0 = fdot2u(w.x, s1, b0); b1 = fdot2u(w.y, s1, b1);
        b2 = fdot2u(w.z, s1, b2); b3 = fdot2u(w.w, s1, b3);
      }
      part4[(ks * 2 + 0) * 64 + j4] = make_float4(a0, a1, a2, a3);
      part4[(ks * 2 + 1) * 64 + j4] = make_float4(b0, b1, b2, b3);
    }
    __syncthreads();
    {
      const int r = tid >> 8, kk = tid & 255;
      float acc = 0.f;
      #pragma unroll
      for (int ks = 0; ks < 8; ++ks) acc += part[(ks * 2 + r) * 256 + kk];
      ods2[r][kk] = acc * C2E;
    }
    __syncthreads();
    // --- B: l[r][t] = SVd - 2*sum_k Vd[k]*rcp(1+exp2(C2E*u + ods2[k]))
    float l_val;
    {
      float a0 = 0.f, a1 = 0.f, a2 = 0.f, a3 = 0.f;
      const float* od = ods2[rB];
      #pragma unroll 2
      for (int ko = 0; ko < 16; ++ko) {
        uint4 u = ud4[ko];
        const int k = kh * 128 + ko * 8;
        a0 = fmaf(VdS[k+0], __builtin_amdgcn_rcpf(1.f + __builtin_amdgcn_exp2f(fmaf(C2E, h2lo(u.x), od[k+0]))), a0);
        a1 = fmaf(VdS[k+1], __builtin_amdgcn_rcpf(1.f + __builtin_amdgcn_exp2f(fmaf(C2E, h2hi(u.x), od[k+1]))), a1);
        a2 = fmaf(VdS[k+2], __builtin_amdgcn_rcpf(1.f + __builtin_amdgcn_exp2f(fmaf(C2E, h2lo(u.y), od[k+2]))), a2);
        a3 = fmaf(VdS[k+3], __builtin_amdgcn_rcpf(1.f + __builtin_amdgcn_exp2f(fmaf(C2E, h2hi(u.y), od[k+3]))), a3);
        a0 = fmaf(VdS[k+4], __builtin_amdgcn_rcpf(1.f + __builtin_amdgcn_exp2f(fmaf(C2E, h2lo(u.z), od[k+4]))), a0);
        a1 = fmaf(VdS[k+5], __builtin_amdgcn_rcpf(1.f + __builtin_amdgcn_exp2f(fmaf(C2E, h2hi(u.z), od[k+5]))), a1);
        a2 = fmaf(VdS[k+6], __builtin_amdgcn_rcpf(1.f + __builtin_amdgcn_exp2f(fmaf(C2E, h2lo(u.w), od[k+6]))), a2);
        a3 = fmaf(VdS[k+7], __builtin_amdgcn_rcpf(1.f + __builtin_amdgcn_exp2f(fmaf(C2E, h2hi(u.w), od[k+7]))), a3);
      }
      float r4 = (a0 + a1) + (a2 + a3);
      r4 += __shfl_xor(r4, 1);
      l_val = fmaf(-2.f, r4, SVd);
    }
    float mx = grp4_max(l_val, red);
    float p  = __builtin_amdgcn_exp2f(L2E * (l_val - mx));
    float sm = grp4_sum(kh == 0 ? p : 0.f, red);
    if (kh == 0) betaT[tB][rB] = p * __builtin_amdgcn_rcpf(sm);
    __syncthreads();
    // --- C: c[r][m] = sum_t beta[r][t]*x1[b][t][m]; 8 tsplits x 16 t
    {
      float c[8];
      #pragma unroll
      for (int e = 0; e < 8; ++e) c[e] = 0.f;
      #pragma unroll 4
      for (int tt = 0; tt < 16; ++tt) {
        const int t = ts * 16 + tt;
        float bv = betaT[t][rb2];
        uint4 u = x14[(size_t)t * 32];
        c[0] = fmaf(bv, h2lo(u.x), c[0]); c[1] = fmaf(bv, h2hi(u.x), c[1]);
        c[2] = fmaf(bv, h2lo(u.y), c[2]); c[3] = fmaf(bv, h2hi(u.y), c[3]);
        c[4] = fmaf(bv, h2lo(u.z), c[4]); c[5] = fmaf(bv, h2hi(u.z), c[5]);
        c[6] = fmaf(bv, h2lo(u.w), c[6]); c[7] = fmaf(bv, h2hi(u.w), c[7]);
      }
      part4[(ts * 2 + rb2) * 64 + m8 * 2]     = make_float4(c[0], c[1], c[2], c[3]);
      part4[(ts * 2 + rb2) * 64 + m8 * 2 + 1] = make_float4(c[4], c[5], c[6], c[7]);
    }
    __syncthreads();
    {
      const int r = tid >> 8, m = tid & 255;
      float v = 0.f;
      #pragma unroll
      for (int t8 = 0; t8 < 8; ++t8) v += part[(t8 * 2 + r) * 256 + m];
      cT[m][r] = v;
    }
    __syncthreads();
    // --- D: y_tilde = [y_t, c] @ Wt^T + bt
    {
      const int r = tid >> 8, i = tid & 255;
      float pv = cT[i][r] * Wt[1 + i];
      float sum = grp4_sum(pv, red);
      if ((tid & 255) == 0) {
        yts[r] = sum + yk[(size_t)(b0 + r) * 128 + step] * Wt[0] + bt0;
      }
    }
    // --- E: gates = d @ Whh_d^T; 2 ksplits x 64 kpairs
    {
      const int j4 = tid & 255, ks = tid >> 8;
      float a0=0,a1=0,a2=0,a3=0,b0=0,b1=0,b2=0,b3=0;
      const int kb = ks * 64;
      #pragma unroll 2
      for (int kp = kb; kp < kb + 64; ++kp) {
        uint4 w = WhhdH4[kp * 256 + j4];
        uint s0 = stH[0][kp], s1 = stH[1][kp];
        a0 = fdot2u(w.x, s0, a0); a1 = fdot2u(w.y, s0, a1);
        a2 = fdot2u(w.z, s0, a2); a3 = fdot2u(w.w, s0, a3);
        b0 = fdot2u(w.x, s1, b0); b1 = fdot2u(w.y, s1, b1);
        b2 = fdot2u(w.z, s1, b2); b3 = fdot2u(w.w, s1, b3);
      }
      part4[(ks * 2 + 0) * 256 + j4] = make_float4(a0, a1, a2, a3);
      part4[(ks * 2 + 1) * 256 + j4] = make_float4(b0, b1, b2, b3);
    }
    __syncthreads();
    // --- update
    {
      const int r = tid >> 8, j = tid & 255;
      float yt = yts[r];
      float z0 = fmaf(yt, wihdS[j],       bdecS[j])       + part[r * 1024 + j]       + part[(2 + r) * 1024 + j];
      float z1 = fmaf(yt, wihdS[256 + j], bdecS[256 + j]) + part[r * 1024 + 256 + j] + part[(2 + r) * 1024 + 256 + j];
      float z2 = fmaf(yt, wihdS[512 + j], bdecS[512 + j]) + part[r * 1024 + 512 + j] + part[(2 + r) * 1024 + 512 + j];
      float z3 = fmaf(yt, wihdS[768 + j], bdecS[768 + j]) + part[r * 1024 + 768 + j] + part[(2 + r) * 1024 + 768 + j];
      float gi = fsig(z0), gf = fsig(z1), gg = fth(z2), go = fsig(z3);
      float c2 = fmaf(gf, c_reg, gi * gg);
      c_reg = c2;
      float d2 = go * fth(c2);
      float dn = __shfl_down(d2, 1);
      float cn = __shfl_down(c2, 1);
      if (!(j & 1)) {
        stH[r][j >> 1] = pk2(d2, dn);
        stH[r][128 + (j >> 1)] = pk2(c2, cn);
      }
    }
    __syncthreads();
  }
  // --- final head: out1 = [d;c] @ W1^T + b1 ; out = out1 @ W2^T + b2
  {
    const int l = tid & 63, ks = tid >> 6;   // 8 ksplits x 64 k
    float a0=0,a1=0,a2=0,a3=0,b0=0,b1=0,b2=0,b3=0;
    const int kb = ks * 64;
    if (ks < 4) {
      for (int k = kb; k < kb + 64; ++k) {
        float4 w = W1T4[k * 64 + l];
        uint u0 = stH[0][k >> 1], u1 = stH[1][k >> 1];
        float d0 = (k & 1) ? h2hi(u0) : h2lo(u0);
        float d1 = (k & 1) ? h2hi(u1) : h2lo(u1);
        a0=fmaf(d0,w.x,a0); a1=fmaf(d0,w.y,a1); a2=fmaf(d0,w.z,a2); a3=fmaf(d0,w.w,a3);
        b0=fmaf(d1,w.x,b0); b1=fmaf(d1,w.y,b1); b2=fmaf(d1,w.z,b2); b3=fmaf(d1,w.w,b3);
      }
    } else {
      for (int k = kb; k < kb + 64; ++k) {
        float4 w = W1T4[k * 64 + l];
        float c0 = cT[k - 256][0], c1 = cT[k - 256][1];
        a0=fmaf(c0,w.x,a0); a1=fmaf(c0,w.y,a1); a2=fmaf(c0,w.z,a2); a3=fmaf(c0,w.w,a3);
        b0=fmaf(c1,w.x,b0); b1=fmaf(c1,w.y,b1); b2=fmaf(c1,w.z,b2); b3=fmaf(c1,w.w,b3);
      }
    }
    part4[(ks * 2 + 0) * 64 + l] = make_float4(a0, a1, a2, a3);
    part4[(ks * 2 + 1) * 64 + l] = make_float4(b0, b1, b2, b3);
  }
  __syncthreads();
  {
    const int r = tid >> 8, q = tid & 255;
    float o1 = b1[q];
    #pragma unroll
    for (int ks = 0; ks < 8; ++ks) o1 += part[(ks * 2 + r) * 256 + q];
    float pv = o1 * W2[q];
    float sum = grp4_sum(pv, red);
    if ((tid & 255) == 0) out[b0 + r] = sum + b2p[0];
  }
}

// ---------------------------------------------------------------------------
extern "C" void kernel_launch(void* const* d_in, const int* in_sizes, int n_in,
                              void* d_out, int out_size, void* d_ws, size_t ws_size,
                              hipStream_t stream)
{
  const float* x       = (const float*)d_in[0];
  const float* y_known = (const float*)d_in[1];
  const float* We      = (const float*)d_in[2];
  const float* Ue      = (const float*)d_in[3];
  const float* Ve      = (const float*)d_in[4];
  const float* Wih_e   = (const float*)d_in[5];
  const float* Whh_e   = (const float*)d_in[6];
  const float* bih_e   = (const float*)d_in[7];
  const float* bhh_e   = (const float*)d_in[8];
  const float* Wd      = (const float*)d_in[9];
  const float* Ud      = (const float*)d_in[10];
  const float* Vd      = (const float*)d_in[11];
  const float* Wih_d   = (const float*)d_in[12];
  const float* Whh_d   = (const float*)d_in[13];
  const float* bih_d   = (const float*)d_in[14];
  const float* bhh_d   = (const float*)d_in[15];
  const float* Wt      = (const float*)d_in[16];
  const float* bt      = (const float*)d_in[17];
  const float* W1      = (const float*)d_in[18];
  const float* b1      = (const float*)d_in[19];
  const float* W2      = (const float*)d_in[20];
  const float* b2      = (const float*)d_in[21];

  float* ws  = (float*)d_ws;
  float* out = (float*)d_out;
  if (ws_size < (size_t)WS_FLOATS * 4u) return;

  uint* wsu  = (uint*)ws;
  uint* x1hU = (uint*)(ws + O_X1H);
  uint* bufU = (uint*)(ws + O_BUF);   // Ux, then Udx

  prep_k<<<(W_FLOATS + 255) / 256, 256, 0, stream>>>(
      We, Wih_e, Whh_e, Wd, Whh_d, W1, Ud, Ue,
      bih_e, bhh_e, bih_d, bhh_d, ws);

  ux_k<<<4096, 256, 0, stream>>>(x, ws + O_UET, bufU);
  encoder_k<<<512, 512, 0, stream>>>(wsu + O_WEH, wsu + O_WENCH,
                                     ws + O_BENC, Ve, bufU, x1hU);
  udx_k<<<4096, 256, 0, stream>>>(x1hU, ws + O_UDT, bufU);
  decoder_k<<<512, 512, 0, stream>>>(wsu + O_WDH, wsu + O_WHHDH,
                                     ws + O_W1T, ws + O_BDEC, Vd, Wih_d,
                                     Wt, bt, b1, W2, b2, y_known,
                                     bufU, x1hU, out);
}